// Round 8
// baseline (384.494 us; speedup 1.0000x reference)
//
#include <hip/hip_runtime.h>
#include <hip/hip_bf16.h>

#define HID1 16
#define NHEAD1 12
#define F1 (HID1*NHEAD1)   // 192
#define HID2 8
#define NHEAD2 8
#define F2 (HID2*NHEAD2)   // 64
#define NUM_FEA 213
#define NEG_SLOPE 0.2f
#define KP 224             // layer-1 K padded to 7*32 for MFMA
#define KP2 192            // layer-2 K (already 6*32)
#define LDK 40             // LDS k-stride (bf16 elems): 80B -> bank stride 20, 2-way max (free)
#define MROWS 128          // gemm block row tile

typedef __attribute__((ext_vector_type(8))) __bf16 bf16x8;
typedef __attribute__((ext_vector_type(4))) float floatx4;
typedef unsigned short ushort_t;

static __device__ __forceinline__ unsigned short f2bf(float f) {
    unsigned u = __float_as_uint(f);
    unsigned r = (u + 0x7fffu + ((u >> 16) & 1u)) >> 16;   // RNE
    return (unsigned short)r;
}
static __device__ __forceinline__ float bf2f(unsigned short u) {
    return __uint_as_float(((unsigned)u) << 16);
}
static __device__ __forceinline__ float lrelu(float e) {
    return e > 0.f ? e : NEG_SLOPE * e;
}
static __device__ __forceinline__ float elu(float v) {
    return v > 0.f ? v : (__expf(v) - 1.f);
}

// ---------------- fused CSR build: one persistent kernel, hand-rolled grid barrier ----
// grid = nsb blocks (<= 256 CUs -> all co-resident; tiny VGPR/LDS). Device-scope
// atomics + threadfence; cross-block scalar reads use atomicAdd(p,0) to bypass
// possibly-stale L1 (G16).

static __device__ __forceinline__ void gbar(int* ctr, int nblk) {
    __syncthreads();
    if (threadIdx.x == 0) {
        __threadfence();
        atomicAdd(ctr, 1);
        while (atomicAdd(ctr, 0) < nblk) __builtin_amdgcn_s_sleep(8);
        __threadfence();
    }
    __syncthreads();
}

__global__ __launch_bounds__(256) void csr_fused_kernel(const int* __restrict__ ei,
                                                        int* __restrict__ cnt,
                                                        int* __restrict__ cnt2,
                                                        int* __restrict__ part,
                                                        int* __restrict__ bsum,
                                                        int* __restrict__ bsum2,
                                                        int* __restrict__ rowstart,
                                                        int* __restrict__ esrc,
                                                        int* __restrict__ bar,
                                                        int E, int N, int Etot) {
    const int nblk = gridDim.x;
    const int tid = threadIdx.x;
    const int gid = blockIdx.x * 256 + tid;
    const int gsz = nblk * 256;
    __shared__ int tmp[256];

    // P0: zero counters
    for (int i = gid; i < N; i += gsz) { cnt[i] = 0; cnt2[i] = 0; }
    gbar(bar + 0, nblk);

    // P1: degree histogram
    for (int e = gid; e < Etot; e += gsz) {
        int d = (e < E) ? ei[E + e] : (e - E);
        atomicAdd(&cnt[d], 1);
    }
    gbar(bar + 1, nblk);

    // P2: per-256-chunk exclusive scan (block b owns chunk b; atomic reads of cnt)
    {
        int i = blockIdx.x * 256 + tid;
        int v = (i < N) ? atomicAdd(&cnt[i], 0) : 0;
        tmp[tid] = v;
        __syncthreads();
        for (int off = 1; off < 256; off <<= 1) {
            int a = (tid >= off) ? tmp[tid - off] : 0;
            __syncthreads();
            tmp[tid] += a;
            __syncthreads();
        }
        if (i < N) part[i] = tmp[tid] - v;
        if (tid == 255) bsum[blockIdx.x] = tmp[255];
    }
    gbar(bar + 2, nblk);

    // P3: block 0 scans block sums (nblk <= 256) into fresh bsum2
    if (blockIdx.x == 0) {
        int v = (tid < nblk) ? atomicAdd(&bsum[tid], 0) : 0;
        tmp[tid] = v;
        __syncthreads();
        for (int off = 1; off < 256; off <<= 1) {
            int a = (tid >= off) ? tmp[tid - off] : 0;
            __syncthreads();
            tmp[tid] += a;
            __syncthreads();
        }
        if (tid < nblk) bsum2[tid] = tmp[tid] - v;
    }
    gbar(bar + 3, nblk);

    // P4: rowstart = part + scanned block sum
    for (int i = gid; i < N; i += gsz) rowstart[i] = part[i] + bsum2[i >> 8];
    if (gid == 0) rowstart[N] = Etot;
    gbar(bar + 4, nblk);

    // P5: fill CSR
    for (int e = gid; e < Etot; e += gsz) {
        int s, d;
        if (e < E) { s = ei[e]; d = ei[E + e]; } else { s = e - E; d = s; }
        esrc[rowstart[d] + atomicAdd(&cnt2[d], 1)] = s;
    }
}

// ---------------- all conversions in one launch ----------------

__global__ void conv_all_kernel(const float* __restrict__ X, ushort_t* __restrict__ Xbf,
                                const float* __restrict__ W1, ushort_t* __restrict__ Wt1,
                                const float* __restrict__ W2, ushort_t* __restrict__ Wt2,
                                int N, long totX) {
    long idx = (long)blockIdx.x * blockDim.x + threadIdx.x;
    if (idx < totX) {
        int r = (int)(idx / KP), k = (int)(idx % KP);
        float v = (r < N && k < NUM_FEA) ? X[(long)r * NUM_FEA + k] : 0.f;
        Xbf[idx] = f2bf(v);
        return;
    }
    long j = idx - totX;
    if (j < F1 * KP) {
        int n = (int)(j / KP), k = (int)(j % KP);
        Wt1[j] = (k < NUM_FEA) ? f2bf(W1[(long)k * F1 + n]) : (ushort_t)0;
        return;
    }
    j -= F1 * KP;
    if (j < F2 * KP2) {
        int n = (int)(j / KP2), k = (int)(j % KP2);
        Wt2[j] = f2bf(W2[(long)k * F2 + n]);
    }
}

// ---------------- GEMM1 via MFMA bf16 ----------------

__global__ __launch_bounds__(256) void gemm1_mfma(const ushort_t* __restrict__ Xbf,
                                                  const ushort_t* __restrict__ Wt,
                                                  ushort_t* __restrict__ Hout, int N) {
    __shared__ ushort_t As[MROWS * LDK];
    __shared__ ushort_t Bs[F1 * LDK];
    int tid = threadIdx.x;
    int wave = tid >> 6, lane = tid & 63;
    int q = lane >> 4, l16 = lane & 15;
    int wm = (wave >> 1) * 64;
    int wn = (wave & 1) * 96;
    long row0 = (long)blockIdx.x * MROWS;

    floatx4 acc[4][6] = {};

    for (int k0 = 0; k0 < KP; k0 += 32) {
#pragma unroll
        for (int p = 0; p < 2; p++) {
            int idx = p * 256 + tid;
            int r = idx >> 2, ks = (idx & 3) * 8;
            *(int4*)&As[r * LDK + ks] = *(const int4*)&Xbf[(row0 + r) * KP + k0 + ks];
        }
#pragma unroll
        for (int p = 0; p < 3; p++) {
            int idx = p * 256 + tid;
            int r = idx >> 2, ks = (idx & 3) * 8;
            *(int4*)&Bs[r * LDK + ks] = *(const int4*)&Wt[(long)r * KP + k0 + ks];
        }
        __syncthreads();
        bf16x8 af[4], bfr[6];
#pragma unroll
        for (int rt = 0; rt < 4; rt++)
            af[rt] = *(const bf16x8*)&As[(wm + rt * 16 + l16) * LDK + q * 8];
#pragma unroll
        for (int ct = 0; ct < 6; ct++)
            bfr[ct] = *(const bf16x8*)&Bs[(wn + ct * 16 + l16) * LDK + q * 8];
#pragma unroll
        for (int rt = 0; rt < 4; rt++)
#pragma unroll
            for (int ct = 0; ct < 6; ct++)
                acc[rt][ct] = __builtin_amdgcn_mfma_f32_16x16x32_bf16(af[rt], bfr[ct], acc[rt][ct], 0, 0, 0);
        __syncthreads();
    }
#pragma unroll
    for (int rt = 0; rt < 4; rt++) {
#pragma unroll
        for (int r = 0; r < 4; r++) {
            long grow = row0 + wm + rt * 16 + q * 4 + r;
            if (grow < N) {
#pragma unroll
                for (int ct = 0; ct < 6; ct++)
                    Hout[grow * F1 + wn + ct * 16 + l16] = f2bf(acc[rt][ct][r]);
            }
        }
    }
}

// ---------------- GEMM2 via MFMA bf16 ----------------

__global__ __launch_bounds__(256) void gemm2_mfma(const ushort_t* __restrict__ Xbf,
                                                  const ushort_t* __restrict__ Wt,
                                                  ushort_t* __restrict__ Hout, int N) {
    __shared__ ushort_t As[MROWS * LDK];
    __shared__ ushort_t Bs[F2 * LDK];
    int tid = threadIdx.x;
    int wave = tid >> 6, lane = tid & 63;
    int q = lane >> 4, l16 = lane & 15;
    int wm = (wave >> 1) * 64;
    int wn = (wave & 1) * 32;
    long row0 = (long)blockIdx.x * MROWS;

    floatx4 acc[4][2] = {};

    for (int k0 = 0; k0 < KP2; k0 += 32) {
#pragma unroll
        for (int p = 0; p < 2; p++) {
            int idx = p * 256 + tid;
            int r = idx >> 2, ks = (idx & 3) * 8;
            *(int4*)&As[r * LDK + ks] = *(const int4*)&Xbf[(row0 + r) * KP2 + k0 + ks];
        }
        {
            int r = tid >> 2, ks = (tid & 3) * 8;
            if (r < F2)
                *(int4*)&Bs[r * LDK + ks] = *(const int4*)&Wt[(long)r * KP2 + k0 + ks];
        }
        __syncthreads();
        bf16x8 af[4], bfr[2];
#pragma unroll
        for (int rt = 0; rt < 4; rt++)
            af[rt] = *(const bf16x8*)&As[(wm + rt * 16 + l16) * LDK + q * 8];
#pragma unroll
        for (int ct = 0; ct < 2; ct++)
            bfr[ct] = *(const bf16x8*)&Bs[(wn + ct * 16 + l16) * LDK + q * 8];
#pragma unroll
        for (int rt = 0; rt < 4; rt++)
#pragma unroll
            for (int ct = 0; ct < 2; ct++)
                acc[rt][ct] = __builtin_amdgcn_mfma_f32_16x16x32_bf16(af[rt], bfr[ct], acc[rt][ct], 0, 0, 0);
        __syncthreads();
    }
#pragma unroll
    for (int rt = 0; rt < 4; rt++) {
#pragma unroll
        for (int r = 0; r < 4; r++) {
            long grow = row0 + wm + rt * 16 + q * 4 + r;
            if (grow < N) {
#pragma unroll
                for (int ct = 0; ct < 2; ct++)
                    Hout[grow * F2 + wn + ct * 16 + l16] = f2bf(acc[rt][ct][r]);
            }
        }
    }
}

// ---------------- attention coefficients (bf16 h) ----------------

template<int H, int C>
__global__ void att_bf_kernel(const ushort_t* __restrict__ h, const float* __restrict__ att_s,
                              const float* __restrict__ att_d, float* __restrict__ as_,
                              float* __restrict__ ad_, int N) {
    int idx = blockIdx.x * blockDim.x + threadIdx.x;
    if (idx >= N * H) return;
    int n = idx / H, hd = idx % H;
    const ushort_t* hp = h + (long)n * H * C + hd * C;
    const float* sp = att_s + hd * C;
    const float* dp = att_d + hd * C;
    float ss = 0.f, dd = 0.f;
#pragma unroll
    for (int c = 0; c < C; c++) {
        float v = bf2f(hp[c]);
        ss += v * sp[c];
        dd += v * dp[c];
    }
    as_[idx] = ss;
    ad_[idx] = dd;
}

// ---------------- gather layer 1: one wave per node, 8B col loads ----------------

__global__ __launch_bounds__(256) void gather1_kernel(const int* __restrict__ rowstart,
                                                      const int* __restrict__ esrc,
                                                      const float* __restrict__ as_,
                                                      const float* __restrict__ ad_,
                                                      const ushort_t* __restrict__ h,
                                                      const float* __restrict__ bias,
                                                      ushort_t* __restrict__ xout, int N) {
    int d = blockIdx.x * 4 + (threadIdx.x >> 6);
    if (d >= N) return;
    int l = threadIdx.x & 63;
    int jc = l < 48 ? l : 47;
    int hj = jc >> 2;
    int e0 = l / 12, h0 = l - e0 * 12;
    int l64 = l + 64;
    int e1 = l64 / 12, h1 = l64 - e1 * 12;
    int beg = rowstart[d], end = rowstart[d + 1];
    float adv0 = ad_[d * NHEAD1 + h0];
    float adv1 = ad_[d * NHEAD1 + h1];
    float4 b4 = ((const float4*)bias)[jc];
    const ushort_t* hcol = h + 4 * jc;

    float acc0 = 0.f, acc1 = 0.f, acc2 = 0.f, acc3 = 0.f, accd = 0.f;

    for (int p = beg; p < end; p += 8) {
        int pp = p + (l & 7);
        int s_l = esrc[pp < end ? pp : beg];
        int s_e[8];
#pragma unroll
        for (int i = 0; i < 8; i++) s_e[i] = __shfl(s_l, i, 64);
        uint2 g[8];
#pragma unroll
        for (int i = 0; i < 8; i++)
            g[i] = *(const uint2*)(hcol + (long)s_e[i] * F1);
        int sq0 = __shfl(s_l, e0, 64);
        int sq1 = __shfl(s_l, e1, 64);
        float a0v = as_[sq0 * NHEAD1 + h0];
        float a1v = as_[sq1 * NHEAD1 + h1];
        float w0 = (p + e0 < end) ? __expf(lrelu(a0v + adv0)) : 0.f;
        float w1 = (e1 < 8 && p + e1 < end) ? __expf(lrelu(a1v + adv1)) : 0.f;
#pragma unroll
        for (int i = 0; i < 8; i++) {
            float wi;
            if (i <= 4) {
                wi = __shfl(w0, i * 12 + hj, 64);
            } else if (i == 5) {
                float wa = __shfl(w0, 60 + hj, 64);
                int srcb = hj >= 4 ? hj - 4 : 0;
                float wb = __shfl(w1, srcb, 64);
                wi = (hj < 4) ? wa : wb;
            } else {
                wi = __shfl(w1, i * 12 + hj - 64, 64);
            }
            unsigned x = g[i].x, y = g[i].y;
            acc0 += wi * __uint_as_float(x << 16);
            acc1 += wi * __uint_as_float(x & 0xffff0000u);
            acc2 += wi * __uint_as_float(y << 16);
            acc3 += wi * __uint_as_float(y & 0xffff0000u);
            accd += wi;
        }
    }
    if (l < 48) {
        float v0 = elu(acc0 / accd + b4.x);
        float v1 = elu(acc1 / accd + b4.y);
        float v2 = elu(acc2 / accd + b4.z);
        float v3 = elu(acc3 / accd + b4.w);
        uint2 outp;
        outp.x = (unsigned)f2bf(v0) | ((unsigned)f2bf(v1) << 16);
        outp.y = (unsigned)f2bf(v2) | ((unsigned)f2bf(v3) << 16);
        *(uint2*)(xout + (long)d * F1 + 4 * l) = outp;
    }
}

// ---------------- gather layer 2: one wave per node, 8B col loads ----------------
// lane l: colgroup cg=l&15 (cols 4cg..4cg+3, head cg>>1), edges l>>4 and (l>>4)+4.
// exp duty: lane j computes w(edge j>>3, head j&7). Final shfl_xor(16,32) reduce.

__global__ __launch_bounds__(256) void gather2_kernel(const int* __restrict__ rowstart,
                                                      const int* __restrict__ esrc,
                                                      const float* __restrict__ as_,
                                                      const float* __restrict__ ad_,
                                                      const ushort_t* __restrict__ h,
                                                      const float* __restrict__ bias,
                                                      float* __restrict__ xout, int N) {
    int d = blockIdx.x * 4 + (threadIdx.x >> 6);
    if (d >= N) return;
    int l = threadIdx.x & 63;
    int cg = l & 15;
    int hj = cg >> 1;
    int e_lo = l >> 4;            // edges e_lo, e_lo+4
    int ie = l >> 3, hq = l & 7;  // exp duty
    int beg = rowstart[d], end = rowstart[d + 1];
    float advq = ad_[d * NHEAD2 + hq];
    const ushort_t* hcol = h + 4 * cg;

    float acc0 = 0.f, acc1 = 0.f, acc2 = 0.f, acc3 = 0.f, accd = 0.f;

    for (int p = beg; p < end; p += 8) {
        int pp = p + (l & 7);
        int s_l = esrc[pp < end ? pp : beg];
        int se0 = __shfl(s_l, e_lo, 64);
        int se1 = __shfl(s_l, e_lo + 4, 64);
        uint2 g0 = *(const uint2*)(hcol + (long)se0 * F2);
        uint2 g1 = *(const uint2*)(hcol + (long)se1 * F2);
        int sq = __shfl(s_l, ie, 64);
        float aval = as_[sq * NHEAD2 + hq];
        float w = (p + ie < end) ? __expf(lrelu(aval + advq)) : 0.f;
        float w0 = __shfl(w, (e_lo << 3) | hj, 64);
        float w1 = __shfl(w, ((e_lo + 4) << 3) | hj, 64);
        unsigned x0 = g0.x, y0 = g0.y, x1 = g1.x, y1 = g1.y;
        acc0 += w0 * __uint_as_float(x0 << 16)        + w1 * __uint_as_float(x1 << 16);
        acc1 += w0 * __uint_as_float(x0 & 0xffff0000u) + w1 * __uint_as_float(x1 & 0xffff0000u);
        acc2 += w0 * __uint_as_float(y0 << 16)        + w1 * __uint_as_float(y1 << 16);
        acc3 += w0 * __uint_as_float(y0 & 0xffff0000u) + w1 * __uint_as_float(y1 & 0xffff0000u);
        accd += w0 + w1;
    }
    // reduce the 4 edge-slices sharing each colgroup
    acc0 += __shfl_xor(acc0, 16, 64); acc0 += __shfl_xor(acc0, 32, 64);
    acc1 += __shfl_xor(acc1, 16, 64); acc1 += __shfl_xor(acc1, 32, 64);
    acc2 += __shfl_xor(acc2, 16, 64); acc2 += __shfl_xor(acc2, 32, 64);
    acc3 += __shfl_xor(acc3, 16, 64); acc3 += __shfl_xor(acc3, 32, 64);
    accd += __shfl_xor(accd, 16, 64); accd += __shfl_xor(accd, 32, 64);
    if (l < 16) {
        float4 b4 = ((const float4*)bias)[cg];
        float4 outp;
        outp.x = elu(acc0 / accd + b4.x);
        outp.y = elu(acc1 / accd + b4.y);
        outp.z = elu(acc2 / accd + b4.z);
        outp.w = elu(acc3 / accd + b4.w);
        *(float4*)(xout + (long)d * F2 + 4 * cg) = outp;
    }
}

// ---------------- pair predictor ----------------

__global__ void pair_kernel(const float* __restrict__ x, const int* __restrict__ n1,
                            const int* __restrict__ n2, const float* __restrict__ linW,
                            const float* __restrict__ linb, float* __restrict__ y, int P) {
    int idx = blockIdx.x * blockDim.x + threadIdx.x;
    if (idx >= P) return;
    const float4* xa = (const float4*)(x + (long)n1[idx] * F2);
    const float4* xb = (const float4*)(x + (long)n2[idx] * F2);
    float a0 = linb[0], a1 = linb[1];
#pragma unroll
    for (int k4 = 0; k4 < F2 / 4; k4++) {
        float4 v = xa[k4];
        int k = k4 * 4;
        a0 += v.x * linW[2 * k] + v.y * linW[2 * (k + 1)] + v.z * linW[2 * (k + 2)] + v.w * linW[2 * (k + 3)];
        a1 += v.x * linW[2 * k + 1] + v.y * linW[2 * (k + 1) + 1] + v.z * linW[2 * (k + 2) + 1] + v.w * linW[2 * (k + 3) + 1];
    }
#pragma unroll
    for (int k4 = 0; k4 < F2 / 4; k4++) {
        float4 v = xb[k4];
        int k = F2 + k4 * 4;
        a0 += v.x * linW[2 * k] + v.y * linW[2 * (k + 1)] + v.z * linW[2 * (k + 2)] + v.w * linW[2 * (k + 3)];
        a1 += v.x * linW[2 * k + 1] + v.y * linW[2 * (k + 1) + 1] + v.z * linW[2 * (k + 2) + 1] + v.w * linW[2 * (k + 3) + 1];
    }
    y[2 * idx]     = 1.f / (1.f + __expf(-a0));
    y[2 * idx + 1] = 1.f / (1.f + __expf(-a1));
}

// ---------------- launch ----------------

extern "C" void kernel_launch(void* const* d_in, const int* in_sizes, int n_in,
                              void* d_out, int out_size, void* d_ws, size_t ws_size,
                              hipStream_t stream) {
    const float* features = (const float*)d_in[0];
    const int*   ei       = (const int*)d_in[1];
    const int*   n1       = (const int*)d_in[2];
    const int*   n2       = (const int*)d_in[3];
    const float* W1       = (const float*)d_in[4];
    const float* att_s1   = (const float*)d_in[5];
    const float* att_d1   = (const float*)d_in[6];
    const float* b1       = (const float*)d_in[7];
    const float* W2       = (const float*)d_in[8];
    const float* att_s2   = (const float*)d_in[9];
    const float* att_d2   = (const float*)d_in[10];
    const float* b2       = (const float*)d_in[11];
    const float* linW     = (const float*)d_in[12];
    const float* linb     = (const float*)d_in[13];

    const int N = in_sizes[0] / NUM_FEA;      // 50000
    const int E = in_sizes[1] / 2;            // 800000
    const int P = in_sizes[2];                // 16384
    const int Etot = E + N;                   // 850000

    const int nblk = (N + MROWS - 1) / MROWS;    // 391
    const int NPAD = nblk * MROWS;               // 50048
    const int nsb = (N + 255) / 256;             // 196 persistent blocks for CSR

    float* ws = (float*)d_ws;
    long o = 0;
    float* h1r  = ws + o; o += (long)N * F1 / 2;             // h1b bf16
    float* xr   = ws + o; o += ((long)NPAD * KP + 1) / 2;    // Xbf then x1bf
    float* as1  = ws + o; o += (long)N * NHEAD1;
    float* ad1  = ws + o; o += (long)N * NHEAD1;
    float* h2r  = ws + o; o += (long)N * F2 / 2;             // h2b bf16
    float* as2  = ws + o; o += (long)N * NHEAD2;
    float* ad2  = ws + o; o += (long)N * NHEAD2;
    float* w1r  = ws + o; o += (F1 * KP + 1) / 2;            // Wt1 bf16
    float* w2r  = ws + o; o += (F2 * KP2 + 1) / 2;           // Wt2 bf16
    int* rowstart = (int*)(ws + o); o += N + 1;
    int* esrc = (int*)(ws + o); o += Etot;
    int* cnt  = (int*)(ws + o); o += N;
    int* cnt2 = (int*)(ws + o); o += N;
    int* part = (int*)(ws + o); o += N;
    int* bsum = (int*)(ws + o); o += 256;
    int* bsum2 = (int*)(ws + o); o += 256;
    int* bar  = (int*)(ws + o); o += 8;

    ushort_t* h1b  = (ushort_t*)h1r;
    ushort_t* Xbf  = (ushort_t*)xr;
    ushort_t* x1bf = (ushort_t*)xr;    // after Xbf dead
    ushort_t* h2b  = (ushort_t*)h2r;
    ushort_t* Wt1  = (ushort_t*)w1r;
    ushort_t* Wt2  = (ushort_t*)w2r;

    float* y_out = (float*)d_out;
    float* x_out = (float*)d_out + (long)2 * P;

    // zero only the grid-barrier counters; cnt/cnt2 zeroed inside csr_fused P0
    hipMemsetAsync(bar, 0, 8 * sizeof(int), stream);

    // CSR build: single persistent-grid kernel
    csr_fused_kernel<<<nsb, 256, 0, stream>>>(ei, cnt, cnt2, part, bsum, bsum2,
                                              rowstart, esrc, bar, E, N, Etot);

    // all dtype conversions in one launch
    long totX = (long)NPAD * KP;
    long totConv = totX + F1 * KP + F2 * KP2;
    conv_all_kernel<<<(int)((totConv + 255) / 256), 256, 0, stream>>>(features, Xbf, W1, Wt1, W2, Wt2, N, totX);

    // layer 1
    gemm1_mfma<<<nblk, 256, 0, stream>>>(Xbf, Wt1, h1b, N);
    att_bf_kernel<NHEAD1, HID1><<<(N * NHEAD1 + 255) / 256, 256, 0, stream>>>(h1b, att_s1, att_d1, as1, ad1, N);
    gather1_kernel<<<(N + 3) / 4, 256, 0, stream>>>(rowstart, esrc, as1, ad1, h1b, b1, x1bf, N);

    // layer 2
    gemm2_mfma<<<nblk, 256, 0, stream>>>(x1bf, Wt2, h2b, N);
    att_bf_kernel<NHEAD2, HID2><<<(N * NHEAD2 + 255) / 256, 256, 0, stream>>>(h2b, att_s2, att_d2, as2, ad2, N);
    gather2_kernel<<<(N + 3) / 4, 256, 0, stream>>>(rowstart, esrc, as2, ad2, h2b, b2, x_out, N);

    // pair predictor
    pair_kernel<<<(P + 255) / 256, 256, 0, stream>>>(x_out, n1, n2, linW, linb, y_out, P);
}

// Round 9
// 361.208 us; speedup vs baseline: 1.0645x; 1.0645x over previous
//
#include <hip/hip_runtime.h>
#include <hip/hip_bf16.h>

#define HID1 16
#define NHEAD1 12
#define F1 (HID1*NHEAD1)   // 192
#define HID2 8
#define NHEAD2 8
#define F2 (HID2*NHEAD2)   // 64
#define NUM_FEA 213
#define NEG_SLOPE 0.2f
#define KP 224             // layer-1 K padded to 7*32 for MFMA
#define KP2 192            // layer-2 K (already 6*32)
#define LDK 40             // LDS k-stride (bf16 elems): 80B -> bank stride 20, 2-way max (free)
#define MROWS 128          // gemm block row tile

typedef __attribute__((ext_vector_type(8))) __bf16 bf16x8;
typedef __attribute__((ext_vector_type(4))) float floatx4;
typedef unsigned short ushort_t;

static __device__ __forceinline__ unsigned short f2bf(float f) {
    unsigned u = __float_as_uint(f);
    unsigned r = (u + 0x7fffu + ((u >> 16) & 1u)) >> 16;   // RNE
    return (unsigned short)r;
}
static __device__ __forceinline__ float bf2f(unsigned short u) {
    return __uint_as_float(((unsigned)u) << 16);
}
static __device__ __forceinline__ float lrelu(float e) {
    return e > 0.f ? e : NEG_SLOPE * e;
}
static __device__ __forceinline__ float elu(float v) {
    return v > 0.f ? v : (__expf(v) - 1.f);
}

// ---------------- fused CSR build ----------------
// Grid barrier: arrive = one RMW (release); poll = atomic LOADS (acquire) --
// concurrent loads to one line don't serialize (R8's RMW-poll cost ~25us/barrier).
// Cross-block stores are write-through (agent atomic store); reads after an
// acquire barrier are plain cached loads (acquire invalidates L1 + XCD-L2).

static __device__ __forceinline__ void gbar(int* ctr, int nblk) {
    __syncthreads();
    if (threadIdx.x == 0) {
        __hip_atomic_fetch_add(ctr, 1, __ATOMIC_RELEASE, __HIP_MEMORY_SCOPE_AGENT);
        while (__hip_atomic_load(ctr, __ATOMIC_ACQUIRE, __HIP_MEMORY_SCOPE_AGENT) < nblk)
            __builtin_amdgcn_s_sleep(2);
    }
    __syncthreads();
}

__global__ __launch_bounds__(256) void csr_fused_kernel(const int* __restrict__ ei,
                                                        int* __restrict__ cnt,
                                                        int* __restrict__ cnt2,
                                                        int* __restrict__ bsum,
                                                        int* __restrict__ rowstart,
                                                        int* __restrict__ esrc,
                                                        int* __restrict__ bar,
                                                        int E, int N, int Etot) {
    const int nblk = gridDim.x;
    const int tid = threadIdx.x;
    const int gid = blockIdx.x * 256 + tid;
    const int gsz = nblk * 256;
    __shared__ int tmp[256];
    __shared__ int borig[256];

    // P0: zero counters (write-through so P1/P5 RMWs at LLC see zeros)
    for (int i = gid; i < N; i += gsz) {
        __hip_atomic_store(&cnt[i], 0, __ATOMIC_RELAXED, __HIP_MEMORY_SCOPE_AGENT);
        __hip_atomic_store(&cnt2[i], 0, __ATOMIC_RELAXED, __HIP_MEMORY_SCOPE_AGENT);
    }
    gbar(bar + 0, nblk);

    // P1: degree histogram
    for (int e = gid; e < Etot; e += gsz) {
        int d = (e < E) ? ei[E + e] : (e - E);
        atomicAdd(&cnt[d], 1);
    }
    gbar(bar + 1, nblk);

    // P2: block-local exclusive scan of own 256-chunk (plain loads post-acquire)
    int v = (gid < N) ? cnt[gid] : 0;
    tmp[tid] = v;
    __syncthreads();
    for (int off = 1; off < 256; off <<= 1) {
        int a = (tid >= off) ? tmp[tid - off] : 0;
        __syncthreads();
        tmp[tid] += a;
        __syncthreads();
    }
    int myexcl = tmp[tid] - v;    // stays in register across barriers
    if (tid == 255)
        __hip_atomic_store(&bsum[blockIdx.x], tmp[255], __ATOMIC_RELAXED, __HIP_MEMORY_SCOPE_AGENT);
    gbar(bar + 2, nblk);

    // P3: every block scans all block sums locally (nblk <= 256)
    {
        int bv = (tid < nblk) ? bsum[tid] : 0;
        tmp[tid] = bv;
        borig[tid] = bv;
        __syncthreads();
        for (int off = 1; off < 256; off <<= 1) {
            int a = (tid >= off) ? tmp[tid - off] : 0;
            __syncthreads();
            tmp[tid] += a;
            __syncthreads();
        }
    }
    int blockbase = tmp[blockIdx.x] - borig[blockIdx.x];

    // P4: rowstart (write-through)
    if (gid < N)
        __hip_atomic_store(&rowstart[gid], myexcl + blockbase, __ATOMIC_RELAXED, __HIP_MEMORY_SCOPE_AGENT);
    if (gid == 0)
        __hip_atomic_store(&rowstart[N], Etot, __ATOMIC_RELAXED, __HIP_MEMORY_SCOPE_AGENT);
    gbar(bar + 3, nblk);

    // P5: fill CSR (plain cached rowstart loads post-acquire)
    for (int e = gid; e < Etot; e += gsz) {
        int s, d;
        if (e < E) { s = ei[e]; d = ei[E + e]; } else { s = e - E; d = s; }
        esrc[rowstart[d] + atomicAdd(&cnt2[d], 1)] = s;
    }
}

// ---------------- all conversions in one launch ----------------

__global__ void conv_all_kernel(const float* __restrict__ X, ushort_t* __restrict__ Xbf,
                                const float* __restrict__ W1, ushort_t* __restrict__ Wt1,
                                const float* __restrict__ W2, ushort_t* __restrict__ Wt2,
                                int N, long totX) {
    long idx = (long)blockIdx.x * blockDim.x + threadIdx.x;
    if (idx < totX) {
        int r = (int)(idx / KP), k = (int)(idx % KP);
        float v = (r < N && k < NUM_FEA) ? X[(long)r * NUM_FEA + k] : 0.f;
        Xbf[idx] = f2bf(v);
        return;
    }
    long j = idx - totX;
    if (j < F1 * KP) {
        int n = (int)(j / KP), k = (int)(j % KP);
        Wt1[j] = (k < NUM_FEA) ? f2bf(W1[(long)k * F1 + n]) : (ushort_t)0;
        return;
    }
    j -= F1 * KP;
    if (j < F2 * KP2) {
        int n = (int)(j / KP2), k = (int)(j % KP2);
        Wt2[j] = f2bf(W2[(long)k * F2 + n]);
    }
}

// ---------------- GEMM1 via MFMA bf16 ----------------

__global__ __launch_bounds__(256) void gemm1_mfma(const ushort_t* __restrict__ Xbf,
                                                  const ushort_t* __restrict__ Wt,
                                                  ushort_t* __restrict__ Hout, int N) {
    __shared__ ushort_t As[MROWS * LDK];
    __shared__ ushort_t Bs[F1 * LDK];
    int tid = threadIdx.x;
    int wave = tid >> 6, lane = tid & 63;
    int q = lane >> 4, l16 = lane & 15;
    int wm = (wave >> 1) * 64;
    int wn = (wave & 1) * 96;
    long row0 = (long)blockIdx.x * MROWS;

    floatx4 acc[4][6] = {};

    for (int k0 = 0; k0 < KP; k0 += 32) {
#pragma unroll
        for (int p = 0; p < 2; p++) {
            int idx = p * 256 + tid;
            int r = idx >> 2, ks = (idx & 3) * 8;
            *(int4*)&As[r * LDK + ks] = *(const int4*)&Xbf[(row0 + r) * KP + k0 + ks];
        }
#pragma unroll
        for (int p = 0; p < 3; p++) {
            int idx = p * 256 + tid;
            int r = idx >> 2, ks = (idx & 3) * 8;
            *(int4*)&Bs[r * LDK + ks] = *(const int4*)&Wt[(long)r * KP + k0 + ks];
        }
        __syncthreads();
        bf16x8 af[4], bfr[6];
#pragma unroll
        for (int rt = 0; rt < 4; rt++)
            af[rt] = *(const bf16x8*)&As[(wm + rt * 16 + l16) * LDK + q * 8];
#pragma unroll
        for (int ct = 0; ct < 6; ct++)
            bfr[ct] = *(const bf16x8*)&Bs[(wn + ct * 16 + l16) * LDK + q * 8];
#pragma unroll
        for (int rt = 0; rt < 4; rt++)
#pragma unroll
            for (int ct = 0; ct < 6; ct++)
                acc[rt][ct] = __builtin_amdgcn_mfma_f32_16x16x32_bf16(af[rt], bfr[ct], acc[rt][ct], 0, 0, 0);
        __syncthreads();
    }
#pragma unroll
    for (int rt = 0; rt < 4; rt++) {
#pragma unroll
        for (int r = 0; r < 4; r++) {
            long grow = row0 + wm + rt * 16 + q * 4 + r;
            if (grow < N) {
#pragma unroll
                for (int ct = 0; ct < 6; ct++)
                    Hout[grow * F1 + wn + ct * 16 + l16] = f2bf(acc[rt][ct][r]);
            }
        }
    }
}

// ---------------- GEMM2 via MFMA bf16 ----------------

__global__ __launch_bounds__(256) void gemm2_mfma(const ushort_t* __restrict__ Xbf,
                                                  const ushort_t* __restrict__ Wt,
                                                  ushort_t* __restrict__ Hout, int N) {
    __shared__ ushort_t As[MROWS * LDK];
    __shared__ ushort_t Bs[F2 * LDK];
    int tid = threadIdx.x;
    int wave = tid >> 6, lane = tid & 63;
    int q = lane >> 4, l16 = lane & 15;
    int wm = (wave >> 1) * 64;
    int wn = (wave & 1) * 32;
    long row0 = (long)blockIdx.x * MROWS;

    floatx4 acc[4][2] = {};

    for (int k0 = 0; k0 < KP2; k0 += 32) {
#pragma unroll
        for (int p = 0; p < 2; p++) {
            int idx = p * 256 + tid;
            int r = idx >> 2, ks = (idx & 3) * 8;
            *(int4*)&As[r * LDK + ks] = *(const int4*)&Xbf[(row0 + r) * KP2 + k0 + ks];
        }
        {
            int r = tid >> 2, ks = (tid & 3) * 8;
            if (r < F2)
                *(int4*)&Bs[r * LDK + ks] = *(const int4*)&Wt[(long)r * KP2 + k0 + ks];
        }
        __syncthreads();
        bf16x8 af[4], bfr[2];
#pragma unroll
        for (int rt = 0; rt < 4; rt++)
            af[rt] = *(const bf16x8*)&As[(wm + rt * 16 + l16) * LDK + q * 8];
#pragma unroll
        for (int ct = 0; ct < 2; ct++)
            bfr[ct] = *(const bf16x8*)&Bs[(wn + ct * 16 + l16) * LDK + q * 8];
#pragma unroll
        for (int rt = 0; rt < 4; rt++)
#pragma unroll
            for (int ct = 0; ct < 2; ct++)
                acc[rt][ct] = __builtin_amdgcn_mfma_f32_16x16x32_bf16(af[rt], bfr[ct], acc[rt][ct], 0, 0, 0);
        __syncthreads();
    }
#pragma unroll
    for (int rt = 0; rt < 4; rt++) {
#pragma unroll
        for (int r = 0; r < 4; r++) {
            long grow = row0 + wm + rt * 16 + q * 4 + r;
            if (grow < N) {
#pragma unroll
                for (int ct = 0; ct < 2; ct++)
                    Hout[grow * F2 + wn + ct * 16 + l16] = f2bf(acc[rt][ct][r]);
            }
        }
    }
}

// ---------------- attention coefficients (bf16 h) ----------------

template<int H, int C>
__global__ void att_bf_kernel(const ushort_t* __restrict__ h, const float* __restrict__ att_s,
                              const float* __restrict__ att_d, float* __restrict__ as_,
                              float* __restrict__ ad_, int N) {
    int idx = blockIdx.x * blockDim.x + threadIdx.x;
    if (idx >= N * H) return;
    int n = idx / H, hd = idx % H;
    const ushort_t* hp = h + (long)n * H * C + hd * C;
    const float* sp = att_s + hd * C;
    const float* dp = att_d + hd * C;
    float ss = 0.f, dd = 0.f;
#pragma unroll
    for (int c = 0; c < C; c++) {
        float v = bf2f(hp[c]);
        ss += v * sp[c];
        dd += v * dp[c];
    }
    as_[idx] = ss;
    ad_[idx] = dd;
}

// ---------------- gather layer 1: one wave per node, 8B col loads ----------------

__global__ __launch_bounds__(256) void gather1_kernel(const int* __restrict__ rowstart,
                                                      const int* __restrict__ esrc,
                                                      const float* __restrict__ as_,
                                                      const float* __restrict__ ad_,
                                                      const ushort_t* __restrict__ h,
                                                      const float* __restrict__ bias,
                                                      ushort_t* __restrict__ xout, int N) {
    int d = blockIdx.x * 4 + (threadIdx.x >> 6);
    if (d >= N) return;
    int l = threadIdx.x & 63;
    int jc = l < 48 ? l : 47;
    int hj = jc >> 2;
    int e0 = l / 12, h0 = l - e0 * 12;
    int l64 = l + 64;
    int e1 = l64 / 12, h1 = l64 - e1 * 12;
    int beg = rowstart[d], end = rowstart[d + 1];
    float adv0 = ad_[d * NHEAD1 + h0];
    float adv1 = ad_[d * NHEAD1 + h1];
    float4 b4 = ((const float4*)bias)[jc];
    const ushort_t* hcol = h + 4 * jc;

    float acc0 = 0.f, acc1 = 0.f, acc2 = 0.f, acc3 = 0.f, accd = 0.f;

    for (int p = beg; p < end; p += 8) {
        int pp = p + (l & 7);
        int s_l = esrc[pp < end ? pp : beg];
        int s_e[8];
#pragma unroll
        for (int i = 0; i < 8; i++) s_e[i] = __shfl(s_l, i, 64);
        uint2 g[8];
#pragma unroll
        for (int i = 0; i < 8; i++)
            g[i] = *(const uint2*)(hcol + (long)s_e[i] * F1);
        int sq0 = __shfl(s_l, e0, 64);
        int sq1 = __shfl(s_l, e1, 64);
        float a0v = as_[sq0 * NHEAD1 + h0];
        float a1v = as_[sq1 * NHEAD1 + h1];
        float w0 = (p + e0 < end) ? __expf(lrelu(a0v + adv0)) : 0.f;
        float w1 = (e1 < 8 && p + e1 < end) ? __expf(lrelu(a1v + adv1)) : 0.f;
#pragma unroll
        for (int i = 0; i < 8; i++) {
            float wi;
            if (i <= 4) {
                wi = __shfl(w0, i * 12 + hj, 64);
            } else if (i == 5) {
                float wa = __shfl(w0, 60 + hj, 64);
                int srcb = hj >= 4 ? hj - 4 : 0;
                float wb = __shfl(w1, srcb, 64);
                wi = (hj < 4) ? wa : wb;
            } else {
                wi = __shfl(w1, i * 12 + hj - 64, 64);
            }
            unsigned x = g[i].x, y = g[i].y;
            acc0 += wi * __uint_as_float(x << 16);
            acc1 += wi * __uint_as_float(x & 0xffff0000u);
            acc2 += wi * __uint_as_float(y << 16);
            acc3 += wi * __uint_as_float(y & 0xffff0000u);
            accd += wi;
        }
    }
    if (l < 48) {
        float v0 = elu(acc0 / accd + b4.x);
        float v1 = elu(acc1 / accd + b4.y);
        float v2 = elu(acc2 / accd + b4.z);
        float v3 = elu(acc3 / accd + b4.w);
        uint2 outp;
        outp.x = (unsigned)f2bf(v0) | ((unsigned)f2bf(v1) << 16);
        outp.y = (unsigned)f2bf(v2) | ((unsigned)f2bf(v3) << 16);
        *(uint2*)(xout + (long)d * F1 + 4 * l) = outp;
    }
}

// ---------------- gather layer 2: one wave per node, 8B col loads ----------------

__global__ __launch_bounds__(256) void gather2_kernel(const int* __restrict__ rowstart,
                                                      const int* __restrict__ esrc,
                                                      const float* __restrict__ as_,
                                                      const float* __restrict__ ad_,
                                                      const ushort_t* __restrict__ h,
                                                      const float* __restrict__ bias,
                                                      float* __restrict__ xout, int N) {
    int d = blockIdx.x * 4 + (threadIdx.x >> 6);
    if (d >= N) return;
    int l = threadIdx.x & 63;
    int cg = l & 15;
    int hj = cg >> 1;
    int e_lo = l >> 4;            // edges e_lo, e_lo+4
    int ie = l >> 3, hq = l & 7;  // exp duty
    int beg = rowstart[d], end = rowstart[d + 1];
    float advq = ad_[d * NHEAD2 + hq];
    const ushort_t* hcol = h + 4 * cg;

    float acc0 = 0.f, acc1 = 0.f, acc2 = 0.f, acc3 = 0.f, accd = 0.f;

    for (int p = beg; p < end; p += 8) {
        int pp = p + (l & 7);
        int s_l = esrc[pp < end ? pp : beg];
        int se0 = __shfl(s_l, e_lo, 64);
        int se1 = __shfl(s_l, e_lo + 4, 64);
        uint2 g0 = *(const uint2*)(hcol + (long)se0 * F2);
        uint2 g1 = *(const uint2*)(hcol + (long)se1 * F2);
        int sq = __shfl(s_l, ie, 64);
        float aval = as_[sq * NHEAD2 + hq];
        float w = (p + ie < end) ? __expf(lrelu(aval + advq)) : 0.f;
        float w0 = __shfl(w, (e_lo << 3) | hj, 64);
        float w1 = __shfl(w, ((e_lo + 4) << 3) | hj, 64);
        unsigned x0 = g0.x, y0 = g0.y, x1 = g1.x, y1 = g1.y;
        acc0 += w0 * __uint_as_float(x0 << 16)        + w1 * __uint_as_float(x1 << 16);
        acc1 += w0 * __uint_as_float(x0 & 0xffff0000u) + w1 * __uint_as_float(x1 & 0xffff0000u);
        acc2 += w0 * __uint_as_float(y0 << 16)        + w1 * __uint_as_float(y1 << 16);
        acc3 += w0 * __uint_as_float(y0 & 0xffff0000u) + w1 * __uint_as_float(y1 & 0xffff0000u);
        accd += w0 + w1;
    }
    acc0 += __shfl_xor(acc0, 16, 64); acc0 += __shfl_xor(acc0, 32, 64);
    acc1 += __shfl_xor(acc1, 16, 64); acc1 += __shfl_xor(acc1, 32, 64);
    acc2 += __shfl_xor(acc2, 16, 64); acc2 += __shfl_xor(acc2, 32, 64);
    acc3 += __shfl_xor(acc3, 16, 64); acc3 += __shfl_xor(acc3, 32, 64);
    accd += __shfl_xor(accd, 16, 64); accd += __shfl_xor(accd, 32, 64);
    if (l < 16) {
        float4 b4 = ((const float4*)bias)[cg];
        float4 outp;
        outp.x = elu(acc0 / accd + b4.x);
        outp.y = elu(acc1 / accd + b4.y);
        outp.z = elu(acc2 / accd + b4.z);
        outp.w = elu(acc3 / accd + b4.w);
        *(float4*)(xout + (long)d * F2 + 4 * cg) = outp;
    }
}

// ---------------- pair predictor ----------------

__global__ void pair_kernel(const float* __restrict__ x, const int* __restrict__ n1,
                            const int* __restrict__ n2, const float* __restrict__ linW,
                            const float* __restrict__ linb, float* __restrict__ y, int P) {
    int idx = blockIdx.x * blockDim.x + threadIdx.x;
    if (idx >= P) return;
    const float4* xa = (const float4*)(x + (long)n1[idx] * F2);
    const float4* xb = (const float4*)(x + (long)n2[idx] * F2);
    float a0 = linb[0], a1 = linb[1];
#pragma unroll
    for (int k4 = 0; k4 < F2 / 4; k4++) {
        float4 v = xa[k4];
        int k = k4 * 4;
        a0 += v.x * linW[2 * k] + v.y * linW[2 * (k + 1)] + v.z * linW[2 * (k + 2)] + v.w * linW[2 * (k + 3)];
        a1 += v.x * linW[2 * k + 1] + v.y * linW[2 * (k + 1) + 1] + v.z * linW[2 * (k + 2) + 1] + v.w * linW[2 * (k + 3) + 1];
    }
#pragma unroll
    for (int k4 = 0; k4 < F2 / 4; k4++) {
        float4 v = xb[k4];
        int k = F2 + k4 * 4;
        a0 += v.x * linW[2 * k] + v.y * linW[2 * (k + 1)] + v.z * linW[2 * (k + 2)] + v.w * linW[2 * (k + 3)];
        a1 += v.x * linW[2 * k + 1] + v.y * linW[2 * (k + 1) + 1] + v.z * linW[2 * (k + 2) + 1] + v.w * linW[2 * (k + 3) + 1];
    }
    y[2 * idx]     = 1.f / (1.f + __expf(-a0));
    y[2 * idx + 1] = 1.f / (1.f + __expf(-a1));
}

// ---------------- launch ----------------

extern "C" void kernel_launch(void* const* d_in, const int* in_sizes, int n_in,
                              void* d_out, int out_size, void* d_ws, size_t ws_size,
                              hipStream_t stream) {
    const float* features = (const float*)d_in[0];
    const int*   ei       = (const int*)d_in[1];
    const int*   n1       = (const int*)d_in[2];
    const int*   n2       = (const int*)d_in[3];
    const float* W1       = (const float*)d_in[4];
    const float* att_s1   = (const float*)d_in[5];
    const float* att_d1   = (const float*)d_in[6];
    const float* b1       = (const float*)d_in[7];
    const float* W2       = (const float*)d_in[8];
    const float* att_s2   = (const float*)d_in[9];
    const float* att_d2   = (const float*)d_in[10];
    const float* b2       = (const float*)d_in[11];
    const float* linW     = (const float*)d_in[12];
    const float* linb     = (const float*)d_in[13];

    const int N = in_sizes[0] / NUM_FEA;      // 50000
    const int E = in_sizes[1] / 2;            // 800000
    const int P = in_sizes[2];                // 16384
    const int Etot = E + N;                   // 850000

    const int nblk = (N + MROWS - 1) / MROWS;    // 391
    const int NPAD = nblk * MROWS;               // 50048
    const int nsb = (N + 255) / 256;             // 196 persistent blocks for CSR

    float* ws = (float*)d_ws;
    long o = 0;
    float* h1r  = ws + o; o += (long)N * F1 / 2;             // h1b bf16
    float* xr   = ws + o; o += ((long)NPAD * KP + 1) / 2;    // Xbf then x1bf
    float* as1  = ws + o; o += (long)N * NHEAD1;
    float* ad1  = ws + o; o += (long)N * NHEAD1;
    float* h2r  = ws + o; o += (long)N * F2 / 2;             // h2b bf16
    float* as2  = ws + o; o += (long)N * NHEAD2;
    float* ad2  = ws + o; o += (long)N * NHEAD2;
    float* w1r  = ws + o; o += (F1 * KP + 1) / 2;            // Wt1 bf16
    float* w2r  = ws + o; o += (F2 * KP2 + 1) / 2;           // Wt2 bf16
    int* rowstart = (int*)(ws + o); o += N + 1;
    int* esrc = (int*)(ws + o); o += Etot;
    int* cnt  = (int*)(ws + o); o += N;
    int* cnt2 = (int*)(ws + o); o += N;
    int* bsum = (int*)(ws + o); o += 256;
    int* bar  = (int*)(ws + o); o += 8;

    ushort_t* h1b  = (ushort_t*)h1r;
    ushort_t* Xbf  = (ushort_t*)xr;
    ushort_t* x1bf = (ushort_t*)xr;    // after Xbf dead
    ushort_t* h2b  = (ushort_t*)h2r;
    ushort_t* Wt1  = (ushort_t*)w1r;
    ushort_t* Wt2  = (ushort_t*)w2r;

    float* y_out = (float*)d_out;
    float* x_out = (float*)d_out + (long)2 * P;

    // zero only the grid-barrier counters; cnt/cnt2 zeroed inside csr_fused P0
    hipMemsetAsync(bar, 0, 8 * sizeof(int), stream);

    // CSR build: single persistent-grid kernel
    csr_fused_kernel<<<nsb, 256, 0, stream>>>(ei, cnt, cnt2, bsum,
                                              rowstart, esrc, bar, E, N, Etot);

    // all dtype conversions in one launch
    long totX = (long)NPAD * KP;
    long totConv = totX + F1 * KP + F2 * KP2;
    conv_all_kernel<<<(int)((totConv + 255) / 256), 256, 0, stream>>>(features, Xbf, W1, Wt1, W2, Wt2, N, totX);

    // layer 1
    gemm1_mfma<<<nblk, 256, 0, stream>>>(Xbf, Wt1, h1b, N);
    att_bf_kernel<NHEAD1, HID1><<<(N * NHEAD1 + 255) / 256, 256, 0, stream>>>(h1b, att_s1, att_d1, as1, ad1, N);
    gather1_kernel<<<(N + 3) / 4, 256, 0, stream>>>(rowstart, esrc, as1, ad1, h1b, b1, x1bf, N);

    // layer 2
    gemm2_mfma<<<nblk, 256, 0, stream>>>(x1bf, Wt2, h2b, N);
    att_bf_kernel<NHEAD2, HID2><<<(N * NHEAD2 + 255) / 256, 256, 0, stream>>>(h2b, att_s2, att_d2, as2, ad2, N);
    gather2_kernel<<<(N + 3) / 4, 256, 0, stream>>>(rowstart, esrc, as2, ad2, h2b, b2, x_out, N);

    // pair predictor
    pair_kernel<<<(P + 255) / 256, 256, 0, stream>>>(x_out, n1, n2, linW, linb, y_out, P);
}

// Round 10
// 345.500 us; speedup vs baseline: 1.1129x; 1.0455x over previous
//
#include <hip/hip_runtime.h>
#include <hip/hip_bf16.h>

#define HID1 16
#define NHEAD1 12
#define F1 (HID1*NHEAD1)   // 192
#define HID2 8
#define NHEAD2 8
#define F2 (HID2*NHEAD2)   // 64
#define NUM_FEA 213
#define NEG_SLOPE 0.2f
#define KP 224             // layer-1 K padded to 7*32 for MFMA
#define KP2 192            // layer-2 K (already 6*32)
#define LDK 40             // LDS k-stride (bf16 elems): 80B -> bank stride 20, 2-way max (free)
#define MROWS 128          // gemm block row tile
#define NC1 224            // gemm1 output cols: 192 h + 12 as + 12 ad + 8 pad
#define NW2R 80            // Wt2 rows: 64 h + 8 as + 8 ad

typedef __attribute__((ext_vector_type(8))) __bf16 bf16x8;
typedef __attribute__((ext_vector_type(4))) float floatx4;
typedef unsigned short ushort_t;

static __device__ __forceinline__ unsigned short f2bf(float f) {
    unsigned u = __float_as_uint(f);
    unsigned r = (u + 0x7fffu + ((u >> 16) & 1u)) >> 16;   // RNE
    return (unsigned short)r;
}
static __device__ __forceinline__ float bf2f(unsigned short u) {
    return __uint_as_float(((unsigned)u) << 16);
}
static __device__ __forceinline__ float lrelu(float e) {
    return e > 0.f ? e : NEG_SLOPE * e;
}
static __device__ __forceinline__ float elu(float v) {
    return v > 0.f ? v : (__expf(v) - 1.f);
}

// ---------------- CSR build (separate big-grid kernels; R8/R9 fused version was
// parallelism-starved: 196 blocks couldn't hide 1.7M atomic latencies) ----------

__global__ void deg_kernel(const int* __restrict__ ei, int* __restrict__ cnt, int E, int Etot) {
    int e = blockIdx.x * blockDim.x + threadIdx.x;
    if (e >= Etot) return;
    int d = (e < E) ? ei[E + e] : (e - E);
    atomicAdd(&cnt[d], 1);
}

__global__ __launch_bounds__(256) void scan1_kernel(const int* __restrict__ cnt,
                                                    int* __restrict__ part,
                                                    int* __restrict__ bsum, int N) {
    __shared__ int tmp[256];
    int tid = threadIdx.x;
    int i = blockIdx.x * 256 + tid;
    int v = (i < N) ? cnt[i] : 0;
    tmp[tid] = v;
    __syncthreads();
    for (int off = 1; off < 256; off <<= 1) {
        int add = (tid >= off) ? tmp[tid - off] : 0;
        __syncthreads();
        tmp[tid] += add;
        __syncthreads();
    }
    if (i < N) part[i] = tmp[tid] - v;
    if (tid == 255) bsum[blockIdx.x] = tmp[255];
}

// scan3 absorbs scan2: every block scans the <=256 block sums locally (1us of
// redundant work buys one fewer dispatch)
__global__ __launch_bounds__(256) void scan3_kernel(const int* __restrict__ part,
                                                    const int* __restrict__ bsum,
                                                    int* __restrict__ rowstart,
                                                    int N, int Etot, int nsb) {
    __shared__ int tmp[256];
    __shared__ int base_s;
    int tid = threadIdx.x;
    int bv = (tid < nsb) ? bsum[tid] : 0;
    tmp[tid] = bv;
    __syncthreads();
    for (int off = 1; off < 256; off <<= 1) {
        int add = (tid >= off) ? tmp[tid - off] : 0;
        __syncthreads();
        tmp[tid] += add;
        __syncthreads();
    }
    if (tid == blockIdx.x) base_s = tmp[tid] - bv;   // exclusive prefix for this chunk
    __syncthreads();
    int i = blockIdx.x * 256 + tid;
    if (i < N) rowstart[i] = part[i] + base_s;
    if (i == 0) rowstart[N] = Etot;
}

__global__ void fill_kernel(const int* __restrict__ ei, const int* __restrict__ rowstart,
                            int* __restrict__ cnt2, int* __restrict__ esrc, int E, int Etot) {
    int e = blockIdx.x * blockDim.x + threadIdx.x;
    if (e >= Etot) return;
    int s, d;
    if (e < E) { s = ei[e]; d = ei[E + e]; } else { s = e - E; d = s; }
    esrc[rowstart[d] + atomicAdd(&cnt2[d], 1)] = s;
}

// ---------------- conversions + attention-vector folding, one launch ----------
// Wt1 n-rows: [0,192)=W1^T, [192,204)=V1s=W1@att_s1, [204,216)=V1d, [216,224)=0
// Wt2 n-rows: [0,64)=W2^T, [64,72)=V2s, [72,80)=V2d

__global__ void conv_all_kernel(const float* __restrict__ X, ushort_t* __restrict__ Xbf,
                                const float* __restrict__ W1, const float* __restrict__ as1w,
                                const float* __restrict__ ad1w, ushort_t* __restrict__ Wt1,
                                const float* __restrict__ W2, const float* __restrict__ as2w,
                                const float* __restrict__ ad2w, ushort_t* __restrict__ Wt2,
                                int N, long totX) {
    long idx = (long)blockIdx.x * blockDim.x + threadIdx.x;
    if (idx < totX) {
        int r = (int)(idx / KP), k = (int)(idx % KP);
        float v = (r < N && k < NUM_FEA) ? X[(long)r * NUM_FEA + k] : 0.f;
        Xbf[idx] = f2bf(v);
        return;
    }
    long j = idx - totX;
    if (j < (long)NC1 * KP) {
        int n = (int)(j / KP), k = (int)(j % KP);
        float v = 0.f;
        if (k < NUM_FEA) {
            if (n < 192) {
                v = W1[(long)k * F1 + n];
            } else if (n < 204) {
                int hd = n - 192;
                for (int c = 0; c < HID1; c++)
                    v += W1[(long)k * F1 + hd * HID1 + c] * as1w[hd * HID1 + c];
            } else if (n < 216) {
                int hd = n - 204;
                for (int c = 0; c < HID1; c++)
                    v += W1[(long)k * F1 + hd * HID1 + c] * ad1w[hd * HID1 + c];
            }
        }
        Wt1[j] = f2bf(v);
        return;
    }
    j -= (long)NC1 * KP;
    if (j < (long)NW2R * KP2) {
        int n = (int)(j / KP2), k = (int)(j % KP2);
        float v;
        if (n < 64) {
            v = W2[(long)k * F2 + n];
        } else if (n < 72) {
            int hd = n - 64;
            v = 0.f;
            for (int c = 0; c < HID2; c++)
                v += W2[(long)k * F2 + hd * HID2 + c] * as2w[hd * HID2 + c];
        } else {
            int hd = n - 72;
            v = 0.f;
            for (int c = 0; c < HID2; c++)
                v += W2[(long)k * F2 + hd * HID2 + c] * ad2w[hd * HID2 + c];
        }
        Wt2[j] = f2bf(v);
    }
}

// ---------------- GEMM1 via MFMA bf16, att coeffs fused as extra columns --------
// block 128 rows x 224 cols; wave: 64 rows x 112 cols = 4x7 tiles of 16x16

__global__ __launch_bounds__(256) void gemm1_mfma(const ushort_t* __restrict__ Xbf,
                                                  const ushort_t* __restrict__ Wt,
                                                  ushort_t* __restrict__ Hout,
                                                  float* __restrict__ as_,
                                                  float* __restrict__ ad_, int N) {
    __shared__ ushort_t As[MROWS * LDK];   // 10 KB
    __shared__ ushort_t Bs[NC1 * LDK];     // 17.5 KB
    int tid = threadIdx.x;
    int wave = tid >> 6, lane = tid & 63;
    int q = lane >> 4, l16 = lane & 15;
    int wm = (wave >> 1) * 64;
    int wn = (wave & 1) * 112;
    long row0 = (long)blockIdx.x * MROWS;

    floatx4 acc[4][7] = {};

    for (int k0 = 0; k0 < KP; k0 += 32) {
#pragma unroll
        for (int p = 0; p < 2; p++) {
            int idx = p * 256 + tid;
            int r = idx >> 2, ks = (idx & 3) * 8;
            *(int4*)&As[r * LDK + ks] = *(const int4*)&Xbf[(row0 + r) * KP + k0 + ks];
        }
#pragma unroll
        for (int p = 0; p < 4; p++) {
            int idx = p * 256 + tid;
            if (idx < NC1 * 4) {
                int r = idx >> 2, ks = (idx & 3) * 8;
                *(int4*)&Bs[r * LDK + ks] = *(const int4*)&Wt[(long)r * KP + k0 + ks];
            }
        }
        __syncthreads();
        bf16x8 af[4], bfr[7];
#pragma unroll
        for (int rt = 0; rt < 4; rt++)
            af[rt] = *(const bf16x8*)&As[(wm + rt * 16 + l16) * LDK + q * 8];
#pragma unroll
        for (int ct = 0; ct < 7; ct++)
            bfr[ct] = *(const bf16x8*)&Bs[(wn + ct * 16 + l16) * LDK + q * 8];
#pragma unroll
        for (int rt = 0; rt < 4; rt++)
#pragma unroll
            for (int ct = 0; ct < 7; ct++)
                acc[rt][ct] = __builtin_amdgcn_mfma_f32_16x16x32_bf16(af[rt], bfr[ct], acc[rt][ct], 0, 0, 0);
        __syncthreads();
    }
#pragma unroll
    for (int rt = 0; rt < 4; rt++) {
#pragma unroll
        for (int r = 0; r < 4; r++) {
            long grow = row0 + wm + rt * 16 + q * 4 + r;
            if (grow < N) {
#pragma unroll
                for (int ct = 0; ct < 7; ct++) {
                    int col = wn + ct * 16 + l16;
                    float v = acc[rt][ct][r];
                    if (col < 192)      Hout[grow * F1 + col] = f2bf(v);
                    else if (col < 204) as_[grow * NHEAD1 + col - 192] = v;
                    else if (col < 216) ad_[grow * NHEAD1 + col - 204] = v;
                }
            }
        }
    }
}

// ---------------- GEMM2 via MFMA bf16, att coeffs fused ----------------
// block 128 rows x 96 cols (80 real); wave: 64 rows x 48 cols = 4x3 tiles

__global__ __launch_bounds__(256) void gemm2_mfma(const ushort_t* __restrict__ Xbf,
                                                  const ushort_t* __restrict__ Wt,
                                                  ushort_t* __restrict__ Hout,
                                                  float* __restrict__ as_,
                                                  float* __restrict__ ad_, int N) {
    __shared__ ushort_t As[MROWS * LDK];
    __shared__ ushort_t Bs[96 * LDK];
    int tid = threadIdx.x;
    int wave = tid >> 6, lane = tid & 63;
    int q = lane >> 4, l16 = lane & 15;
    int wm = (wave >> 1) * 64;
    int wn = (wave & 1) * 48;
    long row0 = (long)blockIdx.x * MROWS;

    floatx4 acc[4][3] = {};

    for (int k0 = 0; k0 < KP2; k0 += 32) {
#pragma unroll
        for (int p = 0; p < 2; p++) {
            int idx = p * 256 + tid;
            int r = idx >> 2, ks = (idx & 3) * 8;
            *(int4*)&As[r * LDK + ks] = *(const int4*)&Xbf[(row0 + r) * KP2 + k0 + ks];
        }
#pragma unroll
        for (int p = 0; p < 2; p++) {
            int idx = p * 256 + tid;
            if (idx < 96 * 4) {
                int r = idx >> 2, ks = (idx & 3) * 8;
                int4 z = {0, 0, 0, 0};
                *(int4*)&Bs[r * LDK + ks] = (r < NW2R) ? *(const int4*)&Wt[(long)r * KP2 + k0 + ks] : z;
            }
        }
        __syncthreads();
        bf16x8 af[4], bfr[3];
#pragma unroll
        for (int rt = 0; rt < 4; rt++)
            af[rt] = *(const bf16x8*)&As[(wm + rt * 16 + l16) * LDK + q * 8];
#pragma unroll
        for (int ct = 0; ct < 3; ct++)
            bfr[ct] = *(const bf16x8*)&Bs[(wn + ct * 16 + l16) * LDK + q * 8];
#pragma unroll
        for (int rt = 0; rt < 4; rt++)
#pragma unroll
            for (int ct = 0; ct < 3; ct++)
                acc[rt][ct] = __builtin_amdgcn_mfma_f32_16x16x32_bf16(af[rt], bfr[ct], acc[rt][ct], 0, 0, 0);
        __syncthreads();
    }
#pragma unroll
    for (int rt = 0; rt < 4; rt++) {
#pragma unroll
        for (int r = 0; r < 4; r++) {
            long grow = row0 + wm + rt * 16 + q * 4 + r;
            if (grow < N) {
#pragma unroll
                for (int ct = 0; ct < 3; ct++) {
                    int col = wn + ct * 16 + l16;
                    float v = acc[rt][ct][r];
                    if (col < 64)      Hout[grow * F2 + col] = f2bf(v);
                    else if (col < 72) as_[grow * NHEAD2 + col - 64] = v;
                    else if (col < 80) ad_[grow * NHEAD2 + col - 72] = v;
                }
            }
        }
    }
}

// ---------------- gather layer 1: one wave per node, 8B col loads ----------------

__global__ __launch_bounds__(256) void gather1_kernel(const int* __restrict__ rowstart,
                                                      const int* __restrict__ esrc,
                                                      const float* __restrict__ as_,
                                                      const float* __restrict__ ad_,
                                                      const ushort_t* __restrict__ h,
                                                      const float* __restrict__ bias,
                                                      ushort_t* __restrict__ xout, int N) {
    int d = blockIdx.x * 4 + (threadIdx.x >> 6);
    if (d >= N) return;
    int l = threadIdx.x & 63;
    int jc = l < 48 ? l : 47;
    int hj = jc >> 2;
    int e0 = l / 12, h0 = l - e0 * 12;
    int l64 = l + 64;
    int e1 = l64 / 12, h1 = l64 - e1 * 12;
    int beg = rowstart[d], end = rowstart[d + 1];
    float adv0 = ad_[d * NHEAD1 + h0];
    float adv1 = ad_[d * NHEAD1 + h1];
    float4 b4 = ((const float4*)bias)[jc];
    const ushort_t* hcol = h + 4 * jc;

    float acc0 = 0.f, acc1 = 0.f, acc2 = 0.f, acc3 = 0.f, accd = 0.f;

    for (int p = beg; p < end; p += 8) {
        int pp = p + (l & 7);
        int s_l = esrc[pp < end ? pp : beg];
        int s_e[8];
#pragma unroll
        for (int i = 0; i < 8; i++) s_e[i] = __shfl(s_l, i, 64);
        uint2 g[8];
#pragma unroll
        for (int i = 0; i < 8; i++)
            g[i] = *(const uint2*)(hcol + (long)s_e[i] * F1);
        int sq0 = __shfl(s_l, e0, 64);
        int sq1 = __shfl(s_l, e1, 64);
        float a0v = as_[sq0 * NHEAD1 + h0];
        float a1v = as_[sq1 * NHEAD1 + h1];
        float w0 = (p + e0 < end) ? __expf(lrelu(a0v + adv0)) : 0.f;
        float w1 = (e1 < 8 && p + e1 < end) ? __expf(lrelu(a1v + adv1)) : 0.f;
#pragma unroll
        for (int i = 0; i < 8; i++) {
            float wi;
            if (i <= 4) {
                wi = __shfl(w0, i * 12 + hj, 64);
            } else if (i == 5) {
                float wa = __shfl(w0, 60 + hj, 64);
                int srcb = hj >= 4 ? hj - 4 : 0;
                float wb = __shfl(w1, srcb, 64);
                wi = (hj < 4) ? wa : wb;
            } else {
                wi = __shfl(w1, i * 12 + hj - 64, 64);
            }
            unsigned x = g[i].x, y = g[i].y;
            acc0 += wi * __uint_as_float(x << 16);
            acc1 += wi * __uint_as_float(x & 0xffff0000u);
            acc2 += wi * __uint_as_float(y << 16);
            acc3 += wi * __uint_as_float(y & 0xffff0000u);
            accd += wi;
        }
    }
    if (l < 48) {
        float v0 = elu(acc0 / accd + b4.x);
        float v1 = elu(acc1 / accd + b4.y);
        float v2 = elu(acc2 / accd + b4.z);
        float v3 = elu(acc3 / accd + b4.w);
        uint2 outp;
        outp.x = (unsigned)f2bf(v0) | ((unsigned)f2bf(v1) << 16);
        outp.y = (unsigned)f2bf(v2) | ((unsigned)f2bf(v3) << 16);
        *(uint2*)(xout + (long)d * F1 + 4 * l) = outp;
    }
}

// ---------------- gather layer 2: one wave per node, 8B col loads ----------------

__global__ __launch_bounds__(256) void gather2_kernel(const int* __restrict__ rowstart,
                                                      const int* __restrict__ esrc,
                                                      const float* __restrict__ as_,
                                                      const float* __restrict__ ad_,
                                                      const ushort_t* __restrict__ h,
                                                      const float* __restrict__ bias,
                                                      float* __restrict__ xout, int N) {
    int d = blockIdx.x * 4 + (threadIdx.x >> 6);
    if (d >= N) return;
    int l = threadIdx.x & 63;
    int cg = l & 15;
    int hj = cg >> 1;
    int e_lo = l >> 4;
    int ie = l >> 3, hq = l & 7;
    int beg = rowstart[d], end = rowstart[d + 1];
    float advq = ad_[d * NHEAD2 + hq];
    const ushort_t* hcol = h + 4 * cg;

    float acc0 = 0.f, acc1 = 0.f, acc2 = 0.f, acc3 = 0.f, accd = 0.f;

    for (int p = beg; p < end; p += 8) {
        int pp = p + (l & 7);
        int s_l = esrc[pp < end ? pp : beg];
        int se0 = __shfl(s_l, e_lo, 64);
        int se1 = __shfl(s_l, e_lo + 4, 64);
        uint2 g0 = *(const uint2*)(hcol + (long)se0 * F2);
        uint2 g1 = *(const uint2*)(hcol + (long)se1 * F2);
        int sq = __shfl(s_l, ie, 64);
        float aval = as_[sq * NHEAD2 + hq];
        float w = (p + ie < end) ? __expf(lrelu(aval + advq)) : 0.f;
        float w0 = __shfl(w, (e_lo << 3) | hj, 64);
        float w1 = __shfl(w, ((e_lo + 4) << 3) | hj, 64);
        unsigned x0 = g0.x, y0 = g0.y, x1 = g1.x, y1 = g1.y;
        acc0 += w0 * __uint_as_float(x0 << 16)        + w1 * __uint_as_float(x1 << 16);
        acc1 += w0 * __uint_as_float(x0 & 0xffff0000u) + w1 * __uint_as_float(x1 & 0xffff0000u);
        acc2 += w0 * __uint_as_float(y0 << 16)        + w1 * __uint_as_float(y1 << 16);
        acc3 += w0 * __uint_as_float(y0 & 0xffff0000u) + w1 * __uint_as_float(y1 & 0xffff0000u);
        accd += w0 + w1;
    }
    acc0 += __shfl_xor(acc0, 16, 64); acc0 += __shfl_xor(acc0, 32, 64);
    acc1 += __shfl_xor(acc1, 16, 64); acc1 += __shfl_xor(acc1, 32, 64);
    acc2 += __shfl_xor(acc2, 16, 64); acc2 += __shfl_xor(acc2, 32, 64);
    acc3 += __shfl_xor(acc3, 16, 64); acc3 += __shfl_xor(acc3, 32, 64);
    accd += __shfl_xor(accd, 16, 64); accd += __shfl_xor(accd, 32, 64);
    if (l < 16) {
        float4 b4 = ((const float4*)bias)[cg];
        float4 outp;
        outp.x = elu(acc0 / accd + b4.x);
        outp.y = elu(acc1 / accd + b4.y);
        outp.z = elu(acc2 / accd + b4.z);
        outp.w = elu(acc3 / accd + b4.w);
        *(float4*)(xout + (long)d * F2 + 4 * cg) = outp;
    }
}

// ---------------- pair predictor ----------------

__global__ void pair_kernel(const float* __restrict__ x, const int* __restrict__ n1,
                            const int* __restrict__ n2, const float* __restrict__ linW,
                            const float* __restrict__ linb, float* __restrict__ y, int P) {
    int idx = blockIdx.x * blockDim.x + threadIdx.x;
    if (idx >= P) return;
    const float4* xa = (const float4*)(x + (long)n1[idx] * F2);
    const float4* xb = (const float4*)(x + (long)n2[idx] * F2);
    float a0 = linb[0], a1 = linb[1];
#pragma unroll
    for (int k4 = 0; k4 < F2 / 4; k4++) {
        float4 v = xa[k4];
        int k = k4 * 4;
        a0 += v.x * linW[2 * k] + v.y * linW[2 * (k + 1)] + v.z * linW[2 * (k + 2)] + v.w * linW[2 * (k + 3)];
        a1 += v.x * linW[2 * k + 1] + v.y * linW[2 * (k + 1) + 1] + v.z * linW[2 * (k + 2) + 1] + v.w * linW[2 * (k + 3) + 1];
    }
#pragma unroll
    for (int k4 = 0; k4 < F2 / 4; k4++) {
        float4 v = xb[k4];
        int k = F2 + k4 * 4;
        a0 += v.x * linW[2 * k] + v.y * linW[2 * (k + 1)] + v.z * linW[2 * (k + 2)] + v.w * linW[2 * (k + 3)];
        a1 += v.x * linW[2 * k + 1] + v.y * linW[2 * (k + 1) + 1] + v.z * linW[2 * (k + 2) + 1] + v.w * linW[2 * (k + 3) + 1];
    }
    y[2 * idx]     = 1.f / (1.f + __expf(-a0));
    y[2 * idx + 1] = 1.f / (1.f + __expf(-a1));
}

// ---------------- launch ----------------

extern "C" void kernel_launch(void* const* d_in, const int* in_sizes, int n_in,
                              void* d_out, int out_size, void* d_ws, size_t ws_size,
                              hipStream_t stream) {
    const float* features = (const float*)d_in[0];
    const int*   ei       = (const int*)d_in[1];
    const int*   n1       = (const int*)d_in[2];
    const int*   n2       = (const int*)d_in[3];
    const float* W1       = (const float*)d_in[4];
    const float* att_s1   = (const float*)d_in[5];
    const float* att_d1   = (const float*)d_in[6];
    const float* b1       = (const float*)d_in[7];
    const float* W2       = (const float*)d_in[8];
    const float* att_s2   = (const float*)d_in[9];
    const float* att_d2   = (const float*)d_in[10];
    const float* b2       = (const float*)d_in[11];
    const float* linW     = (const float*)d_in[12];
    const float* linb     = (const float*)d_in[13];

    const int N = in_sizes[0] / NUM_FEA;      // 50000
    const int E = in_sizes[1] / 2;            // 800000
    const int P = in_sizes[2];                // 16384
    const int Etot = E + N;                   // 850000

    const int nblk = (N + MROWS - 1) / MROWS;    // 391
    const int NPAD = nblk * MROWS;               // 50048
    const int nsb = (N + 255) / 256;             // 196

    float* ws = (float*)d_ws;
    long o = 0;
    float* h1r  = ws + o; o += (long)N * F1 / 2;             // h1b bf16
    float* xr   = ws + o; o += ((long)NPAD * KP + 1) / 2;    // Xbf then x1bf
    float* as1  = ws + o; o += (long)N * NHEAD1;
    float* ad1  = ws + o; o += (long)N * NHEAD1;
    float* h2r  = ws + o; o += (long)N * F2 / 2;             // h2b bf16
    float* as2  = ws + o; o += (long)N * NHEAD2;
    float* ad2  = ws + o; o += (long)N * NHEAD2;
    float* w1r  = ws + o; o += ((long)NC1 * KP + 1) / 2;     // Wt1 bf16 (incl att cols)
    float* w2r  = ws + o; o += ((long)NW2R * KP2 + 1) / 2;   // Wt2 bf16 (incl att cols)
    int* rowstart = (int*)(ws + o); o += N + 1;
    int* esrc = (int*)(ws + o); o += Etot;
    int* cnt  = (int*)(ws + o); o += N;
    int* cnt2 = (int*)(ws + o); o += N;
    int* part = (int*)(ws + o); o += N;
    int* bsum = (int*)(ws + o); o += 256;

    ushort_t* h1b  = (ushort_t*)h1r;
    ushort_t* Xbf  = (ushort_t*)xr;
    ushort_t* x1bf = (ushort_t*)xr;    // after Xbf dead
    ushort_t* h2b  = (ushort_t*)h2r;
    ushort_t* Wt1  = (ushort_t*)w1r;
    ushort_t* Wt2  = (ushort_t*)w2r;

    float* y_out = (float*)d_out;
    float* x_out = (float*)d_out + (long)2 * P;

    hipMemsetAsync(cnt, 0, (size_t)2 * N * sizeof(int), stream);

    // CSR build (4 dispatches, big grids)
    deg_kernel<<<(Etot + 255) / 256, 256, 0, stream>>>(ei, cnt, E, Etot);
    scan1_kernel<<<nsb, 256, 0, stream>>>(cnt, part, bsum, N);
    scan3_kernel<<<nsb, 256, 0, stream>>>(part, bsum, rowstart, N, Etot, nsb);
    fill_kernel<<<(Etot + 255) / 256, 256, 0, stream>>>(ei, rowstart, cnt2, esrc, E, Etot);

    // conversions + folded attention vectors
    long totX = (long)NPAD * KP;
    long totConv = totX + (long)NC1 * KP + (long)NW2R * KP2;
    conv_all_kernel<<<(int)((totConv + 255) / 256), 256, 0, stream>>>(
        features, Xbf, W1, att_s1, att_d1, Wt1, W2, att_s2, att_d2, Wt2, N, totX);

    // layer 1 (gemm computes h1 + as1 + ad1)
    gemm1_mfma<<<nblk, 256, 0, stream>>>(Xbf, Wt1, h1b, as1, ad1, N);
    gather1_kernel<<<(N + 3) / 4, 256, 0, stream>>>(rowstart, esrc, as1, ad1, h1b, b1, x1bf, N);

    // layer 2 (gemm computes h2 + as2 + ad2)
    gemm2_mfma<<<nblk, 256, 0, stream>>>(x1bf, Wt2, h2b, as2, ad2, N);
    gather2_kernel<<<(N + 3) / 4, 256, 0, stream>>>(rowstart, esrc, as2, ad2, h2b, b2, x_out, N);

    // pair predictor
    pair_kernel<<<(P + 255) / 256, 256, 0, stream>>>(x_out, n1, n2, linW, linb, y_out, P);
}

// Round 11
// 307.019 us; speedup vs baseline: 1.2523x; 1.1253x over previous
//
#include <hip/hip_runtime.h>
#include <hip/hip_bf16.h>

#define HID1 16
#define NHEAD1 12
#define F1 (HID1*NHEAD1)   // 192
#define HID2 8
#define NHEAD2 8
#define F2 (HID2*NHEAD2)   // 64
#define NUM_FEA 213
#define NEG_SLOPE 0.2f
#define KP 224             // layer-1 K padded to 7*32 for MFMA
#define KP2 192            // layer-2 K (already 6*32)
#define LDK 40             // LDS k-stride (bf16 elems): 80B -> bank stride 20, 2-way max (free)
#define MROWS 128          // gemm block row tile
#define NC1 224            // gemm1 output cols: 192 h + 12 as + 12 ad + 8 pad
#define NW2R 80            // Wt2 rows: 64 h + 8 as + 8 ad
#define NCVB 4096          // conv blocks inside conv||deg combo

typedef __attribute__((ext_vector_type(8))) __bf16 bf16x8;
typedef __attribute__((ext_vector_type(4))) float floatx4;
typedef unsigned short ushort_t;

static __device__ __forceinline__ unsigned short f2bf(float f) {
    unsigned u = __float_as_uint(f);
    unsigned r = (u + 0x7fffu + ((u >> 16) & 1u)) >> 16;   // RNE
    return (unsigned short)r;
}
static __device__ __forceinline__ float bf2f(unsigned short u) {
    return __uint_as_float(((unsigned)u) << 16);
}
static __device__ __forceinline__ float lrelu(float e) {
    return e > 0.f ? e : NEG_SLOPE * e;
}
static __device__ __forceinline__ float elu(float v) {
    return v > 0.f ? v : (__expf(v) - 1.f);
}

// ---------------- combo 1: conversions+att-fold (grid-stride) || degree histogram ----
// Wt1 n-rows: [0,192)=W1^T, [192,204)=V1s=W1@att_s1, [204,216)=V1d, [216,224)=0
// Wt2 n-rows: [0,64)=W2^T, [64,72)=V2s, [72,80)=V2d
// deg also records epos[e] (per-edge slot) so fill needs no atomics.

__global__ __launch_bounds__(256) void conv_deg_kernel(
        const float* __restrict__ X, ushort_t* __restrict__ Xbf,
        const float* __restrict__ W1, const float* __restrict__ as1w,
        const float* __restrict__ ad1w, ushort_t* __restrict__ Wt1,
        const float* __restrict__ W2, const float* __restrict__ as2w,
        const float* __restrict__ ad2w, ushort_t* __restrict__ Wt2,
        const int* __restrict__ ei, int* __restrict__ cnt, int* __restrict__ epos,
        int N, long totX, long totConv, int E, int Etot) {
    if ((int)blockIdx.x >= NCVB) {
        // degree part
        int e = ((int)blockIdx.x - NCVB) * 256 + threadIdx.x;
        if (e < Etot) {
            int d = (e < E) ? ei[E + e] : (e - E);
            epos[e] = atomicAdd(&cnt[d], 1);
        }
        return;
    }
    const long gsz = (long)NCVB * 256;
    for (long idx = (long)blockIdx.x * 256 + threadIdx.x; idx < totConv; idx += gsz) {
        if (idx < totX) {
            int r = (int)(idx / KP), k = (int)(idx % KP);
            float v = (r < N && k < NUM_FEA) ? X[(long)r * NUM_FEA + k] : 0.f;
            Xbf[idx] = f2bf(v);
            continue;
        }
        long j = idx - totX;
        if (j < (long)NC1 * KP) {
            int n = (int)(j / KP), k = (int)(j % KP);
            float v = 0.f;
            if (k < NUM_FEA) {
                if (n < 192) {
                    v = W1[(long)k * F1 + n];
                } else if (n < 204) {
                    int hd = n - 192;
                    for (int c = 0; c < HID1; c++)
                        v += W1[(long)k * F1 + hd * HID1 + c] * as1w[hd * HID1 + c];
                } else if (n < 216) {
                    int hd = n - 204;
                    for (int c = 0; c < HID1; c++)
                        v += W1[(long)k * F1 + hd * HID1 + c] * ad1w[hd * HID1 + c];
                }
            }
            Wt1[j] = f2bf(v);
            continue;
        }
        j -= (long)NC1 * KP;
        if (j < (long)NW2R * KP2) {
            int n = (int)(j / KP2), k = (int)(j % KP2);
            float v;
            if (n < 64) {
                v = W2[(long)k * F2 + n];
            } else if (n < 72) {
                int hd = n - 64;
                v = 0.f;
                for (int c = 0; c < HID2; c++)
                    v += W2[(long)k * F2 + hd * HID2 + c] * as2w[hd * HID2 + c];
            } else {
                int hd = n - 72;
                v = 0.f;
                for (int c = 0; c < HID2; c++)
                    v += W2[(long)k * F2 + hd * HID2 + c] * ad2w[hd * HID2 + c];
            }
            Wt2[j] = f2bf(v);
        }
    }
}

// ---------------- CSR scans ----------------

__global__ __launch_bounds__(256) void scan1_kernel(const int* __restrict__ cnt,
                                                    int* __restrict__ part,
                                                    int* __restrict__ bsum, int N) {
    __shared__ int tmp[256];
    int tid = threadIdx.x;
    int i = blockIdx.x * 256 + tid;
    int v = (i < N) ? cnt[i] : 0;
    tmp[tid] = v;
    __syncthreads();
    for (int off = 1; off < 256; off <<= 1) {
        int add = (tid >= off) ? tmp[tid - off] : 0;
        __syncthreads();
        tmp[tid] += add;
        __syncthreads();
    }
    if (i < N) part[i] = tmp[tid] - v;
    if (tid == 255) bsum[blockIdx.x] = tmp[255];
}

__global__ __launch_bounds__(256) void scan3_kernel(const int* __restrict__ part,
                                                    const int* __restrict__ bsum,
                                                    int* __restrict__ rowstart,
                                                    int N, int Etot, int nsb) {
    __shared__ int tmp[256];
    __shared__ int base_s;
    int tid = threadIdx.x;
    int bv = (tid < nsb) ? bsum[tid] : 0;
    tmp[tid] = bv;
    __syncthreads();
    for (int off = 1; off < 256; off <<= 1) {
        int add = (tid >= off) ? tmp[tid - off] : 0;
        __syncthreads();
        tmp[tid] += add;
        __syncthreads();
    }
    if (tid == blockIdx.x) base_s = tmp[tid] - bv;
    __syncthreads();
    int i = blockIdx.x * 256 + tid;
    if (i < N) rowstart[i] = part[i] + base_s;
    if (i == 0) rowstart[N] = Etot;
}

// ---------------- combo 2: GEMM1 (att fused) || CSR fill (atomic-free) ----------

__global__ __launch_bounds__(256) void gemm1_fill_kernel(
        const ushort_t* __restrict__ Xbf, const ushort_t* __restrict__ Wt,
        ushort_t* __restrict__ Hout, float* __restrict__ as_, float* __restrict__ ad_,
        const int* __restrict__ ei, const int* __restrict__ rowstart,
        const int* __restrict__ epos, int* __restrict__ esrc,
        int N, int E, int Etot, int nblk_gemm) {
    if ((int)blockIdx.x >= nblk_gemm) {
        // fill part: pure scatter, no atomics
        int e = ((int)blockIdx.x - nblk_gemm) * 256 + threadIdx.x;
        if (e < Etot) {
            int s, d;
            if (e < E) { s = ei[e]; d = ei[E + e]; } else { s = e - E; d = s; }
            esrc[rowstart[d] + epos[e]] = s;
        }
        return;
    }
    __shared__ ushort_t As[MROWS * LDK];   // 10 KB
    __shared__ ushort_t Bs[NC1 * LDK];     // 17.5 KB
    int tid = threadIdx.x;
    int wave = tid >> 6, lane = tid & 63;
    int q = lane >> 4, l16 = lane & 15;
    int wm = (wave >> 1) * 64;
    int wn = (wave & 1) * 112;
    long row0 = (long)blockIdx.x * MROWS;

    floatx4 acc[4][7] = {};

    for (int k0 = 0; k0 < KP; k0 += 32) {
#pragma unroll
        for (int p = 0; p < 2; p++) {
            int idx = p * 256 + tid;
            int r = idx >> 2, ks = (idx & 3) * 8;
            *(int4*)&As[r * LDK + ks] = *(const int4*)&Xbf[(row0 + r) * KP + k0 + ks];
        }
#pragma unroll
        for (int p = 0; p < 4; p++) {
            int idx = p * 256 + tid;
            if (idx < NC1 * 4) {
                int r = idx >> 2, ks = (idx & 3) * 8;
                *(int4*)&Bs[r * LDK + ks] = *(const int4*)&Wt[(long)r * KP + k0 + ks];
            }
        }
        __syncthreads();
        bf16x8 af[4], bfr[7];
#pragma unroll
        for (int rt = 0; rt < 4; rt++)
            af[rt] = *(const bf16x8*)&As[(wm + rt * 16 + l16) * LDK + q * 8];
#pragma unroll
        for (int ct = 0; ct < 7; ct++)
            bfr[ct] = *(const bf16x8*)&Bs[(wn + ct * 16 + l16) * LDK + q * 8];
#pragma unroll
        for (int rt = 0; rt < 4; rt++)
#pragma unroll
            for (int ct = 0; ct < 7; ct++)
                acc[rt][ct] = __builtin_amdgcn_mfma_f32_16x16x32_bf16(af[rt], bfr[ct], acc[rt][ct], 0, 0, 0);
        __syncthreads();
    }
#pragma unroll
    for (int rt = 0; rt < 4; rt++) {
#pragma unroll
        for (int r = 0; r < 4; r++) {
            long grow = row0 + wm + rt * 16 + q * 4 + r;
            if (grow < N) {
#pragma unroll
                for (int ct = 0; ct < 7; ct++) {
                    int col = wn + ct * 16 + l16;
                    float v = acc[rt][ct][r];
                    if (col < 192)      Hout[grow * F1 + col] = f2bf(v);
                    else if (col < 204) as_[grow * NHEAD1 + col - 192] = v;
                    else if (col < 216) ad_[grow * NHEAD1 + col - 204] = v;
                }
            }
        }
    }
}

// ---------------- GEMM2 via MFMA bf16, att coeffs fused ----------------

__global__ __launch_bounds__(256) void gemm2_mfma(const ushort_t* __restrict__ Xbf,
                                                  const ushort_t* __restrict__ Wt,
                                                  ushort_t* __restrict__ Hout,
                                                  float* __restrict__ as_,
                                                  float* __restrict__ ad_, int N) {
    __shared__ ushort_t As[MROWS * LDK];
    __shared__ ushort_t Bs[96 * LDK];
    int tid = threadIdx.x;
    int wave = tid >> 6, lane = tid & 63;
    int q = lane >> 4, l16 = lane & 15;
    int wm = (wave >> 1) * 64;
    int wn = (wave & 1) * 48;
    long row0 = (long)blockIdx.x * MROWS;

    floatx4 acc[4][3] = {};

    for (int k0 = 0; k0 < KP2; k0 += 32) {
#pragma unroll
        for (int p = 0; p < 2; p++) {
            int idx = p * 256 + tid;
            int r = idx >> 2, ks = (idx & 3) * 8;
            *(int4*)&As[r * LDK + ks] = *(const int4*)&Xbf[(row0 + r) * KP2 + k0 + ks];
        }
#pragma unroll
        for (int p = 0; p < 2; p++) {
            int idx = p * 256 + tid;
            if (idx < 96 * 4) {
                int r = idx >> 2, ks = (idx & 3) * 8;
                int4 z = {0, 0, 0, 0};
                *(int4*)&Bs[r * LDK + ks] = (r < NW2R) ? *(const int4*)&Wt[(long)r * KP2 + k0 + ks] : z;
            }
        }
        __syncthreads();
        bf16x8 af[4], bfr[3];
#pragma unroll
        for (int rt = 0; rt < 4; rt++)
            af[rt] = *(const bf16x8*)&As[(wm + rt * 16 + l16) * LDK + q * 8];
#pragma unroll
        for (int ct = 0; ct < 3; ct++)
            bfr[ct] = *(const bf16x8*)&Bs[(wn + ct * 16 + l16) * LDK + q * 8];
#pragma unroll
        for (int rt = 0; rt < 4; rt++)
#pragma unroll
            for (int ct = 0; ct < 3; ct++)
                acc[rt][ct] = __builtin_amdgcn_mfma_f32_16x16x32_bf16(af[rt], bfr[ct], acc[rt][ct], 0, 0, 0);
        __syncthreads();
    }
#pragma unroll
    for (int rt = 0; rt < 4; rt++) {
#pragma unroll
        for (int r = 0; r < 4; r++) {
            long grow = row0 + wm + rt * 16 + q * 4 + r;
            if (grow < N) {
#pragma unroll
                for (int ct = 0; ct < 3; ct++) {
                    int col = wn + ct * 16 + l16;
                    float v = acc[rt][ct][r];
                    if (col < 64)      Hout[grow * F2 + col] = f2bf(v);
                    else if (col < 72) as_[grow * NHEAD2 + col - 64] = v;
                    else if (col < 80) ad_[grow * NHEAD2 + col - 72] = v;
                }
            }
        }
    }
}

// ---------------- gather layer 1: one wave/node, 16-edge chunks, 16 8B loads in flight ----
// lane owns cols 4jc..4jc+3 (head jc>>2). Exp duties: slots l, l+64, l+128 of the
// 16x12=192 (edge,head) grid. Accumulation order identical to the 8-chunk version.

__global__ __launch_bounds__(256) void gather1_kernel(const int* __restrict__ rowstart,
                                                      const int* __restrict__ esrc,
                                                      const float* __restrict__ as_,
                                                      const float* __restrict__ ad_,
                                                      const ushort_t* __restrict__ h,
                                                      const float* __restrict__ bias,
                                                      ushort_t* __restrict__ xout, int N) {
    int d = blockIdx.x * 4 + (threadIdx.x >> 6);
    if (d >= N) return;
    int l = threadIdx.x & 63;
    int jc = l < 48 ? l : 47;
    int hj = jc >> 2;
    int e0 = l / 12,          h0 = l - e0 * 12;
    int e1 = (l + 64) / 12,   h1 = (l + 64) - e1 * 12;
    int e2 = (l + 128) / 12,  h2 = (l + 128) - e2 * 12;
    int beg = rowstart[d], end = rowstart[d + 1];
    float adv0 = ad_[d * NHEAD1 + h0];
    float adv1 = ad_[d * NHEAD1 + h1];
    float adv2 = ad_[d * NHEAD1 + h2];
    float4 b4 = ((const float4*)bias)[jc];
    const ushort_t* hcol = h + 4 * jc;

    float acc0 = 0.f, acc1 = 0.f, acc2 = 0.f, acc3 = 0.f, accd = 0.f;

    for (int p = beg; p < end; p += 16) {
        int pp = p + (l & 15);
        int s_l = esrc[pp < end ? pp : beg];
        int s_e[16];
#pragma unroll
        for (int i = 0; i < 16; i++) s_e[i] = __shfl(s_l, i, 64);
        uint2 g[16];
#pragma unroll
        for (int i = 0; i < 16; i++)
            g[i] = *(const uint2*)(hcol + (long)s_e[i] * F1);
        int sq0 = __shfl(s_l, e0, 64);
        int sq1 = __shfl(s_l, e1, 64);
        int sq2 = __shfl(s_l, e2, 64);
        float a0v = as_[sq0 * NHEAD1 + h0];
        float a1v = as_[sq1 * NHEAD1 + h1];
        float a2v = as_[sq2 * NHEAD1 + h2];
        float w0 = (p + e0 < end) ? __expf(lrelu(a0v + adv0)) : 0.f;
        float w1 = (p + e1 < end) ? __expf(lrelu(a1v + adv1)) : 0.f;
        float w2 = (p + e2 < end) ? __expf(lrelu(a2v + adv2)) : 0.f;
#pragma unroll
        for (int i = 0; i < 16; i++) {
            float wi;
            if (i < 5) {
                wi = __shfl(w0, i * 12 + hj, 64);
            } else if (i == 5) {
                float wa = __shfl(w0, 60 + hj, 64);
                float wb = __shfl(w1, hj >= 4 ? hj - 4 : 0, 64);
                wi = (hj < 4) ? wa : wb;
            } else if (i < 10) {
                wi = __shfl(w1, i * 12 + hj - 64, 64);
            } else if (i == 10) {
                float wa = __shfl(w1, 56 + hj, 64);
                float wb = __shfl(w2, hj >= 8 ? hj - 8 : 0, 64);
                wi = (hj < 8) ? wa : wb;
            } else {
                wi = __shfl(w2, i * 12 + hj - 128, 64);
            }
            unsigned x = g[i].x, y = g[i].y;
            acc0 += wi * __uint_as_float(x << 16);
            acc1 += wi * __uint_as_float(x & 0xffff0000u);
            acc2 += wi * __uint_as_float(y << 16);
            acc3 += wi * __uint_as_float(y & 0xffff0000u);
            accd += wi;
        }
    }
    if (l < 48) {
        float v0 = elu(acc0 / accd + b4.x);
        float v1 = elu(acc1 / accd + b4.y);
        float v2 = elu(acc2 / accd + b4.z);
        float v3 = elu(acc3 / accd + b4.w);
        uint2 outp;
        outp.x = (unsigned)f2bf(v0) | ((unsigned)f2bf(v1) << 16);
        outp.y = (unsigned)f2bf(v2) | ((unsigned)f2bf(v3) << 16);
        *(uint2*)(xout + (long)d * F1 + 4 * l) = outp;
    }
}

// ---------------- gather layer 2: one wave/node, 16-edge chunks ----------------
// lane: colgroup cg=l&15, edges e_lo+4k (k=0..3); duties: slot l and l+64 of the
// 16x8=128 (edge,head) grid. Final shfl_xor(16,32) reduce.

__global__ __launch_bounds__(256) void gather2_kernel(const int* __restrict__ rowstart,
                                                      const int* __restrict__ esrc,
                                                      const float* __restrict__ as_,
                                                      const float* __restrict__ ad_,
                                                      const ushort_t* __restrict__ h,
                                                      const float* __restrict__ bias,
                                                      float* __restrict__ xout, int N) {
    int d = blockIdx.x * 4 + (threadIdx.x >> 6);
    if (d >= N) return;
    int l = threadIdx.x & 63;
    int cg = l & 15;
    int hj = cg >> 1;
    int e_lo = l >> 4;
    int ie0 = l >> 3, hq = l & 7;
    int ie1 = 8 + ie0;
    int beg = rowstart[d], end = rowstart[d + 1];
    float advq = ad_[d * NHEAD2 + hq];
    const ushort_t* hcol = h + 4 * cg;

    float acc0 = 0.f, acc1 = 0.f, acc2 = 0.f, acc3 = 0.f, accd = 0.f;

    for (int p = beg; p < end; p += 16) {
        int pp = p + (l & 15);
        int s_l = esrc[pp < end ? pp : beg];
        int se[4];
#pragma unroll
        for (int k = 0; k < 4; k++) se[k] = __shfl(s_l, e_lo + 4 * k, 64);
        uint2 g[4];
#pragma unroll
        for (int k = 0; k < 4; k++)
            g[k] = *(const uint2*)(hcol + (long)se[k] * F2);
        int sq0 = __shfl(s_l, ie0, 64);
        int sq1 = __shfl(s_l, ie1, 64);
        float a0v = as_[sq0 * NHEAD2 + hq];
        float a1v = as_[sq1 * NHEAD2 + hq];
        float w0d = (p + ie0 < end) ? __expf(lrelu(a0v + advq)) : 0.f;
        float w1d = (p + ie1 < end) ? __expf(lrelu(a1v + advq)) : 0.f;
#pragma unroll
        for (int k = 0; k < 4; k++) {
            int i = e_lo + 4 * k;
            float wk = (k < 2) ? __shfl(w0d, i * 8 + hj, 64)
                               : __shfl(w1d, i * 8 + hj - 64, 64);
            unsigned x = g[k].x, y = g[k].y;
            acc0 += wk * __uint_as_float(x << 16);
            acc1 += wk * __uint_as_float(x & 0xffff0000u);
            acc2 += wk * __uint_as_float(y << 16);
            acc3 += wk * __uint_as_float(y & 0xffff0000u);
            accd += wk;
        }
    }
    acc0 += __shfl_xor(acc0, 16, 64); acc0 += __shfl_xor(acc0, 32, 64);
    acc1 += __shfl_xor(acc1, 16, 64); acc1 += __shfl_xor(acc1, 32, 64);
    acc2 += __shfl_xor(acc2, 16, 64); acc2 += __shfl_xor(acc2, 32, 64);
    acc3 += __shfl_xor(acc3, 16, 64); acc3 += __shfl_xor(acc3, 32, 64);
    accd += __shfl_xor(accd, 16, 64); accd += __shfl_xor(accd, 32, 64);
    if (l < 16) {
        float4 b4 = ((const float4*)bias)[cg];
        float4 outp;
        outp.x = elu(acc0 / accd + b4.x);
        outp.y = elu(acc1 / accd + b4.y);
        outp.z = elu(acc2 / accd + b4.z);
        outp.w = elu(acc3 / accd + b4.w);
        *(float4*)(xout + (long)d * F2 + 4 * cg) = outp;
    }
}

// ---------------- pair predictor ----------------

__global__ void pair_kernel(const float* __restrict__ x, const int* __restrict__ n1,
                            const int* __restrict__ n2, const float* __restrict__ linW,
                            const float* __restrict__ linb, float* __restrict__ y, int P) {
    int idx = blockIdx.x * blockDim.x + threadIdx.x;
    if (idx >= P) return;
    const float4* xa = (const float4*)(x + (long)n1[idx] * F2);
    const float4* xb = (const float4*)(x + (long)n2[idx] * F2);
    float a0 = linb[0], a1 = linb[1];
#pragma unroll
    for (int k4 = 0; k4 < F2 / 4; k4++) {
        float4 v = xa[k4];
        int k = k4 * 4;
        a0 += v.x * linW[2 * k] + v.y * linW[2 * (k + 1)] + v.z * linW[2 * (k + 2)] + v.w * linW[2 * (k + 3)];
        a1 += v.x * linW[2 * k + 1] + v.y * linW[2 * (k + 1) + 1] + v.z * linW[2 * (k + 2) + 1] + v.w * linW[2 * (k + 3) + 1];
    }
#pragma unroll
    for (int k4 = 0; k4 < F2 / 4; k4++) {
        float4 v = xb[k4];
        int k = F2 + k4 * 4;
        a0 += v.x * linW[2 * k] + v.y * linW[2 * (k + 1)] + v.z * linW[2 * (k + 2)] + v.w * linW[2 * (k + 3)];
        a1 += v.x * linW[2 * k + 1] + v.y * linW[2 * (k + 1) + 1] + v.z * linW[2 * (k + 2) + 1] + v.w * linW[2 * (k + 3) + 1];
    }
    y[2 * idx]     = 1.f / (1.f + __expf(-a0));
    y[2 * idx + 1] = 1.f / (1.f + __expf(-a1));
}

// ---------------- launch ----------------

extern "C" void kernel_launch(void* const* d_in, const int* in_sizes, int n_in,
                              void* d_out, int out_size, void* d_ws, size_t ws_size,
                              hipStream_t stream) {
    const float* features = (const float*)d_in[0];
    const int*   ei       = (const int*)d_in[1];
    const int*   n1       = (const int*)d_in[2];
    const int*   n2       = (const int*)d_in[3];
    const float* W1       = (const float*)d_in[4];
    const float* att_s1   = (const float*)d_in[5];
    const float* att_d1   = (const float*)d_in[6];
    const float* b1       = (const float*)d_in[7];
    const float* W2       = (const float*)d_in[8];
    const float* att_s2   = (const float*)d_in[9];
    const float* att_d2   = (const float*)d_in[10];
    const float* b2       = (const float*)d_in[11];
    const float* linW     = (const float*)d_in[12];
    const float* linb     = (const float*)d_in[13];

    const int N = in_sizes[0] / NUM_FEA;      // 50000
    const int E = in_sizes[1] / 2;            // 800000
    const int P = in_sizes[2];                // 16384
    const int Etot = E + N;                   // 850000

    const int nblk = (N + MROWS - 1) / MROWS;    // 391
    const int NPAD = nblk * MROWS;               // 50048
    const int nsb = (N + 255) / 256;             // 196
    const int ndeg = (Etot + 255) / 256;         // 3321

    float* ws = (float*)d_ws;
    long o = 0;
    float* h1r  = ws + o; o += (long)N * F1 / 2;             // h1b bf16
    float* xr   = ws + o; o += ((long)NPAD * KP + 1) / 2;    // Xbf then x1bf
    float* as1  = ws + o; o += (long)N * NHEAD1;
    float* ad1  = ws + o; o += (long)N * NHEAD1;
    float* h2r  = ws + o; o += (long)N * F2 / 2;             // h2b bf16
    float* as2  = ws + o; o += (long)N * NHEAD2;
    float* ad2  = ws + o; o += (long)N * NHEAD2;
    float* w1r  = ws + o; o += ((long)NC1 * KP + 1) / 2;     // Wt1 bf16 (incl att cols)
    float* w2r  = ws + o; o += ((long)NW2R * KP2 + 1) / 2;   // Wt2 bf16 (incl att cols)
    int* rowstart = (int*)(ws + o); o += N + 1;
    int* esrc = (int*)(ws + o); o += Etot;
    int* epos = (int*)(ws + o); o += Etot;
    int* cnt  = (int*)(ws + o); o += N;
    int* part = (int*)(ws + o); o += N;
    int* bsum = (int*)(ws + o); o += 256;

    ushort_t* h1b  = (ushort_t*)h1r;
    ushort_t* Xbf  = (ushort_t*)xr;
    ushort_t* x1bf = (ushort_t*)xr;    // after Xbf dead
    ushort_t* h2b  = (ushort_t*)h2r;
    ushort_t* Wt1  = (ushort_t*)w1r;
    ushort_t* Wt2  = (ushort_t*)w2r;

    float* y_out = (float*)d_out;
    float* x_out = (float*)d_out + (long)2 * P;

    hipMemsetAsync(cnt, 0, (size_t)N * sizeof(int), stream);

    long totX = (long)NPAD * KP;
    long totConv = totX + (long)NC1 * KP + (long)NW2R * KP2;

    // combo 1: conversions || degree histogram (+epos)
    conv_deg_kernel<<<NCVB + ndeg, 256, 0, stream>>>(
        features, Xbf, W1, att_s1, att_d1, Wt1, W2, att_s2, att_d2, Wt2,
        ei, cnt, epos, N, totX, totConv, E, Etot);

    // scans
    scan1_kernel<<<nsb, 256, 0, stream>>>(cnt, part, bsum, N);
    scan3_kernel<<<nsb, 256, 0, stream>>>(part, bsum, rowstart, N, Etot, nsb);

    // combo 2: GEMM1 (h1 + as1 + ad1) || CSR fill
    gemm1_fill_kernel<<<nblk + ndeg, 256, 0, stream>>>(
        Xbf, Wt1, h1b, as1, ad1, ei, rowstart, epos, esrc, N, E, Etot, nblk);

    gather1_kernel<<<(N + 3) / 4, 256, 0, stream>>>(rowstart, esrc, as1, ad1, h1b, b1, x1bf, N);

    // layer 2
    gemm2_mfma<<<nblk, 256, 0, stream>>>(x1bf, Wt2, h2b, as2, ad2, N);
    gather2_kernel<<<(N + 3) / 4, 256, 0, stream>>>(rowstart, esrc, as2, ad2, h2b, b2, x_out, N);

    // pair predictor
    pair_kernel<<<(P + 255) / 256, 256, 0, stream>>>(x_out, n1, n2, linW, linb, y_out, P);
}

// Round 12
// 294.803 us; speedup vs baseline: 1.3042x; 1.0414x over previous
//
#include <hip/hip_runtime.h>
#include <hip/hip_bf16.h>

#define HID1 16
#define NHEAD1 12
#define F1 (HID1*NHEAD1)   // 192
#define HID2 8
#define NHEAD2 8
#define F2 (HID2*NHEAD2)   // 64
#define NUM_FEA 213
#define NEG_SLOPE 0.2f
#define KP 224             // layer-1 K padded to 7*32 for MFMA
#define KP2 192            // layer-2 K (already 6*32)
#define LDK 40             // LDS k-stride (bf16 elems): 80B -> bank stride 20, 2-way max (free)
#define MROWS 128          // gemm block row tile
#define NC1 224            // gemm1 output cols: 192 h + 12 as + 12 ad + 8 pad
#define NW2R 80            // Wt2 rows: 64 h + 8 as + 8 ad
#define NCVB 4096          // conv blocks inside conv||deg combo

typedef __attribute__((ext_vector_type(8))) __bf16 bf16x8;
typedef __attribute__((ext_vector_type(4))) float floatx4;
typedef unsigned short ushort_t;

static __device__ __forceinline__ unsigned short f2bf(float f) {
    unsigned u = __float_as_uint(f);
    unsigned r = (u + 0x7fffu + ((u >> 16) & 1u)) >> 16;   // RNE
    return (unsigned short)r;
}
static __device__ __forceinline__ float bf2f(unsigned short u) {
    return __uint_as_float(((unsigned)u) << 16);
}
static __device__ __forceinline__ float lrelu(float e) {
    return e > 0.f ? e : NEG_SLOPE * e;
}
static __device__ __forceinline__ float elu(float v) {
    return v > 0.f ? v : (__expf(v) - 1.f);
}

// ---------------- combo 1: conversions+att-fold (grid-stride) || degree histogram ----

__global__ __launch_bounds__(256) void conv_deg_kernel(
        const float* __restrict__ X, ushort_t* __restrict__ Xbf,
        const float* __restrict__ W1, const float* __restrict__ as1w,
        const float* __restrict__ ad1w, ushort_t* __restrict__ Wt1,
        const float* __restrict__ W2, const float* __restrict__ as2w,
        const float* __restrict__ ad2w, ushort_t* __restrict__ Wt2,
        const int* __restrict__ ei, int* __restrict__ cnt, int* __restrict__ epos,
        int N, long totX, long totConv, int E, int Etot) {
    if ((int)blockIdx.x >= NCVB) {
        int e = ((int)blockIdx.x - NCVB) * 256 + threadIdx.x;
        if (e < Etot) {
            int d = (e < E) ? ei[E + e] : (e - E);
            epos[e] = atomicAdd(&cnt[d], 1);
        }
        return;
    }
    const long gsz = (long)NCVB * 256;
    for (long idx = (long)blockIdx.x * 256 + threadIdx.x; idx < totConv; idx += gsz) {
        if (idx < totX) {
            int r = (int)(idx / KP), k = (int)(idx % KP);
            float v = (r < N && k < NUM_FEA) ? X[(long)r * NUM_FEA + k] : 0.f;
            Xbf[idx] = f2bf(v);
            continue;
        }
        long j = idx - totX;
        if (j < (long)NC1 * KP) {
            int n = (int)(j / KP), k = (int)(j % KP);
            float v = 0.f;
            if (k < NUM_FEA) {
                if (n < 192) {
                    v = W1[(long)k * F1 + n];
                } else if (n < 204) {
                    int hd = n - 192;
                    for (int c = 0; c < HID1; c++)
                        v += W1[(long)k * F1 + hd * HID1 + c] * as1w[hd * HID1 + c];
                } else if (n < 216) {
                    int hd = n - 204;
                    for (int c = 0; c < HID1; c++)
                        v += W1[(long)k * F1 + hd * HID1 + c] * ad1w[hd * HID1 + c];
                }
            }
            Wt1[j] = f2bf(v);
            continue;
        }
        j -= (long)NC1 * KP;
        if (j < (long)NW2R * KP2) {
            int n = (int)(j / KP2), k = (int)(j % KP2);
            float v;
            if (n < 64) {
                v = W2[(long)k * F2 + n];
            } else if (n < 72) {
                int hd = n - 64;
                v = 0.f;
                for (int c = 0; c < HID2; c++)
                    v += W2[(long)k * F2 + hd * HID2 + c] * as2w[hd * HID2 + c];
            } else {
                int hd = n - 72;
                v = 0.f;
                for (int c = 0; c < HID2; c++)
                    v += W2[(long)k * F2 + hd * HID2 + c] * ad2w[hd * HID2 + c];
            }
            Wt2[j] = f2bf(v);
        }
    }
}

// ---------------- CSR scans ----------------

__global__ __launch_bounds__(256) void scan1_kernel(const int* __restrict__ cnt,
                                                    int* __restrict__ part,
                                                    int* __restrict__ bsum, int N) {
    __shared__ int tmp[256];
    int tid = threadIdx.x;
    int i = blockIdx.x * 256 + tid;
    int v = (i < N) ? cnt[i] : 0;
    tmp[tid] = v;
    __syncthreads();
    for (int off = 1; off < 256; off <<= 1) {
        int add = (tid >= off) ? tmp[tid - off] : 0;
        __syncthreads();
        tmp[tid] += add;
        __syncthreads();
    }
    if (i < N) part[i] = tmp[tid] - v;
    if (tid == 255) bsum[blockIdx.x] = tmp[255];
}

__global__ __launch_bounds__(256) void scan3_kernel(const int* __restrict__ part,
                                                    const int* __restrict__ bsum,
                                                    int* __restrict__ rowstart,
                                                    int N, int Etot, int nsb) {
    __shared__ int tmp[256];
    __shared__ int base_s;
    int tid = threadIdx.x;
    int bv = (tid < nsb) ? bsum[tid] : 0;
    tmp[tid] = bv;
    __syncthreads();
    for (int off = 1; off < 256; off <<= 1) {
        int add = (tid >= off) ? tmp[tid - off] : 0;
        __syncthreads();
        tmp[tid] += add;
        __syncthreads();
    }
    if (tid == blockIdx.x) base_s = tmp[tid] - bv;
    __syncthreads();
    int i = blockIdx.x * 256 + tid;
    if (i < N) rowstart[i] = part[i] + base_s;
    if (i == 0) rowstart[N] = Etot;
}

// ---------------- combo 2: GEMM1 (att fused) || CSR fill (atomic-free) ----------

__global__ __launch_bounds__(256) void gemm1_fill_kernel(
        const ushort_t* __restrict__ Xbf, const ushort_t* __restrict__ Wt,
        ushort_t* __restrict__ Hout, float* __restrict__ as_, float* __restrict__ ad_,
        const int* __restrict__ ei, const int* __restrict__ rowstart,
        const int* __restrict__ epos, int* __restrict__ esrc,
        int N, int E, int Etot, int nblk_gemm) {
    if ((int)blockIdx.x >= nblk_gemm) {
        int e = ((int)blockIdx.x - nblk_gemm) * 256 + threadIdx.x;
        if (e < Etot) {
            int s, d;
            if (e < E) { s = ei[e]; d = ei[E + e]; } else { s = e - E; d = s; }
            esrc[rowstart[d] + epos[e]] = s;
        }
        return;
    }
    __shared__ ushort_t As[MROWS * LDK];   // 10 KB
    __shared__ ushort_t Bs[NC1 * LDK];     // 17.5 KB
    int tid = threadIdx.x;
    int wave = tid >> 6, lane = tid & 63;
    int q = lane >> 4, l16 = lane & 15;
    int wm = (wave >> 1) * 64;
    int wn = (wave & 1) * 112;
    long row0 = (long)blockIdx.x * MROWS;

    floatx4 acc[4][7] = {};

    for (int k0 = 0; k0 < KP; k0 += 32) {
#pragma unroll
        for (int p = 0; p < 2; p++) {
            int idx = p * 256 + tid;
            int r = idx >> 2, ks = (idx & 3) * 8;
            *(int4*)&As[r * LDK + ks] = *(const int4*)&Xbf[(row0 + r) * KP + k0 + ks];
        }
#pragma unroll
        for (int p = 0; p < 4; p++) {
            int idx = p * 256 + tid;
            if (idx < NC1 * 4) {
                int r = idx >> 2, ks = (idx & 3) * 8;
                *(int4*)&Bs[r * LDK + ks] = *(const int4*)&Wt[(long)r * KP + k0 + ks];
            }
        }
        __syncthreads();
        bf16x8 af[4], bfr[7];
#pragma unroll
        for (int rt = 0; rt < 4; rt++)
            af[rt] = *(const bf16x8*)&As[(wm + rt * 16 + l16) * LDK + q * 8];
#pragma unroll
        for (int ct = 0; ct < 7; ct++)
            bfr[ct] = *(const bf16x8*)&Bs[(wn + ct * 16 + l16) * LDK + q * 8];
#pragma unroll
        for (int rt = 0; rt < 4; rt++)
#pragma unroll
            for (int ct = 0; ct < 7; ct++)
                acc[rt][ct] = __builtin_amdgcn_mfma_f32_16x16x32_bf16(af[rt], bfr[ct], acc[rt][ct], 0, 0, 0);
        __syncthreads();
    }
#pragma unroll
    for (int rt = 0; rt < 4; rt++) {
#pragma unroll
        for (int r = 0; r < 4; r++) {
            long grow = row0 + wm + rt * 16 + q * 4 + r;
            if (grow < N) {
#pragma unroll
                for (int ct = 0; ct < 7; ct++) {
                    int col = wn + ct * 16 + l16;
                    float v = acc[rt][ct][r];
                    if (col < 192)      Hout[grow * F1 + col] = f2bf(v);
                    else if (col < 204) as_[grow * NHEAD1 + col - 192] = v;
                    else if (col < 216) ad_[grow * NHEAD1 + col - 204] = v;
                }
            }
        }
    }
}

// ---------------- GEMM2 via MFMA bf16, att coeffs fused ----------------

__global__ __launch_bounds__(256) void gemm2_mfma(const ushort_t* __restrict__ Xbf,
                                                  const ushort_t* __restrict__ Wt,
                                                  ushort_t* __restrict__ Hout,
                                                  float* __restrict__ as_,
                                                  float* __restrict__ ad_, int N) {
    __shared__ ushort_t As[MROWS * LDK];
    __shared__ ushort_t Bs[96 * LDK];
    int tid = threadIdx.x;
    int wave = tid >> 6, lane = tid & 63;
    int q = lane >> 4, l16 = lane & 15;
    int wm = (wave >> 1) * 64;
    int wn = (wave & 1) * 48;
    long row0 = (long)blockIdx.x * MROWS;

    floatx4 acc[4][3] = {};

    for (int k0 = 0; k0 < KP2; k0 += 32) {
#pragma unroll
        for (int p = 0; p < 2; p++) {
            int idx = p * 256 + tid;
            int r = idx >> 2, ks = (idx & 3) * 8;
            *(int4*)&As[r * LDK + ks] = *(const int4*)&Xbf[(row0 + r) * KP2 + k0 + ks];
        }
#pragma unroll
        for (int p = 0; p < 2; p++) {
            int idx = p * 256 + tid;
            if (idx < 96 * 4) {
                int r = idx >> 2, ks = (idx & 3) * 8;
                int4 z = {0, 0, 0, 0};
                *(int4*)&Bs[r * LDK + ks] = (r < NW2R) ? *(const int4*)&Wt[(long)r * KP2 + k0 + ks] : z;
            }
        }
        __syncthreads();
        bf16x8 af[4], bfr[3];
#pragma unroll
        for (int rt = 0; rt < 4; rt++)
            af[rt] = *(const bf16x8*)&As[(wm + rt * 16 + l16) * LDK + q * 8];
#pragma unroll
        for (int ct = 0; ct < 3; ct++)
            bfr[ct] = *(const bf16x8*)&Bs[(wn + ct * 16 + l16) * LDK + q * 8];
#pragma unroll
        for (int rt = 0; rt < 4; rt++)
#pragma unroll
            for (int ct = 0; ct < 3; ct++)
                acc[rt][ct] = __builtin_amdgcn_mfma_f32_16x16x32_bf16(af[rt], bfr[ct], acc[rt][ct], 0, 0, 0);
        __syncthreads();
    }
#pragma unroll
    for (int rt = 0; rt < 4; rt++) {
#pragma unroll
        for (int r = 0; r < 4; r++) {
            long grow = row0 + wm + rt * 16 + q * 4 + r;
            if (grow < N) {
#pragma unroll
                for (int ct = 0; ct < 3; ct++) {
                    int col = wn + ct * 16 + l16;
                    float v = acc[rt][ct][r];
                    if (col < 64)      Hout[grow * F2 + col] = f2bf(v);
                    else if (col < 72) as_[grow * NHEAD2 + col - 64] = v;
                    else if (col < 80) ad_[grow * NHEAD2 + col - 72] = v;
                }
            }
        }
    }
}

// ---------------- gather layer 1: one wave/node, 8-edge chunks (R10 version) ---------
// 16-edge variant (R11) hit a VGPR cliff: 60 VGPR -> 34% occupancy -> 75us vs 60us.
// 8 uint2 in flight, VGPR 36, occupancy ~58% is the sweet spot.

__global__ __launch_bounds__(256) void gather1_kernel(const int* __restrict__ rowstart,
                                                      const int* __restrict__ esrc,
                                                      const float* __restrict__ as_,
                                                      const float* __restrict__ ad_,
                                                      const ushort_t* __restrict__ h,
                                                      const float* __restrict__ bias,
                                                      ushort_t* __restrict__ xout, int N) {
    int d = blockIdx.x * 4 + (threadIdx.x >> 6);
    if (d >= N) return;
    int l = threadIdx.x & 63;
    int jc = l < 48 ? l : 47;
    int hj = jc >> 2;
    int e0 = l / 12, h0 = l - e0 * 12;
    int l64 = l + 64;
    int e1 = l64 / 12, h1 = l64 - e1 * 12;
    int beg = rowstart[d], end = rowstart[d + 1];
    float adv0 = ad_[d * NHEAD1 + h0];
    float adv1 = ad_[d * NHEAD1 + h1];
    float4 b4 = ((const float4*)bias)[jc];
    const ushort_t* hcol = h + 4 * jc;

    float acc0 = 0.f, acc1 = 0.f, acc2 = 0.f, acc3 = 0.f, accd = 0.f;

    for (int p = beg; p < end; p += 8) {
        int pp = p + (l & 7);
        int s_l = esrc[pp < end ? pp : beg];
        int s_e[8];
#pragma unroll
        for (int i = 0; i < 8; i++) s_e[i] = __shfl(s_l, i, 64);
        uint2 g[8];
#pragma unroll
        for (int i = 0; i < 8; i++)
            g[i] = *(const uint2*)(hcol + (long)s_e[i] * F1);
        int sq0 = __shfl(s_l, e0, 64);
        int sq1 = __shfl(s_l, e1, 64);
        float a0v = as_[sq0 * NHEAD1 + h0];
        float a1v = as_[sq1 * NHEAD1 + h1];
        float w0 = (p + e0 < end) ? __expf(lrelu(a0v + adv0)) : 0.f;
        float w1 = (e1 < 8 && p + e1 < end) ? __expf(lrelu(a1v + adv1)) : 0.f;
#pragma unroll
        for (int i = 0; i < 8; i++) {
            float wi;
            if (i <= 4) {
                wi = __shfl(w0, i * 12 + hj, 64);
            } else if (i == 5) {
                float wa = __shfl(w0, 60 + hj, 64);
                int srcb = hj >= 4 ? hj - 4 : 0;
                float wb = __shfl(w1, srcb, 64);
                wi = (hj < 4) ? wa : wb;
            } else {
                wi = __shfl(w1, i * 12 + hj - 64, 64);
            }
            unsigned x = g[i].x, y = g[i].y;
            acc0 += wi * __uint_as_float(x << 16);
            acc1 += wi * __uint_as_float(x & 0xffff0000u);
            acc2 += wi * __uint_as_float(y << 16);
            acc3 += wi * __uint_as_float(y & 0xffff0000u);
            accd += wi;
        }
    }
    if (l < 48) {
        float v0 = elu(acc0 / accd + b4.x);
        float v1 = elu(acc1 / accd + b4.y);
        float v2 = elu(acc2 / accd + b4.z);
        float v3 = elu(acc3 / accd + b4.w);
        uint2 outp;
        outp.x = (unsigned)f2bf(v0) | ((unsigned)f2bf(v1) << 16);
        outp.y = (unsigned)f2bf(v2) | ((unsigned)f2bf(v3) << 16);
        *(uint2*)(xout + (long)d * F1 + 4 * l) = outp;
    }
}

// ---------------- gather layer 2: one wave/node, 16-edge chunks ----------------

__global__ __launch_bounds__(256) void gather2_kernel(const int* __restrict__ rowstart,
                                                      const int* __restrict__ esrc,
                                                      const float* __restrict__ as_,
                                                      const float* __restrict__ ad_,
                                                      const ushort_t* __restrict__ h,
                                                      const float* __restrict__ bias,
                                                      float* __restrict__ xout, int N) {
    int d = blockIdx.x * 4 + (threadIdx.x >> 6);
    if (d >= N) return;
    int l = threadIdx.x & 63;
    int cg = l & 15;
    int hj = cg >> 1;
    int e_lo = l >> 4;
    int ie0 = l >> 3, hq = l & 7;
    int ie1 = 8 + ie0;
    int beg = rowstart[d], end = rowstart[d + 1];
    float advq = ad_[d * NHEAD2 + hq];
    const ushort_t* hcol = h + 4 * cg;

    float acc0 = 0.f, acc1 = 0.f, acc2 = 0.f, acc3 = 0.f, accd = 0.f;

    for (int p = beg; p < end; p += 16) {
        int pp = p + (l & 15);
        int s_l = esrc[pp < end ? pp : beg];
        int se[4];
#pragma unroll
        for (int k = 0; k < 4; k++) se[k] = __shfl(s_l, e_lo + 4 * k, 64);
        uint2 g[4];
#pragma unroll
        for (int k = 0; k < 4; k++)
            g[k] = *(const uint2*)(hcol + (long)se[k] * F2);
        int sq0 = __shfl(s_l, ie0, 64);
        int sq1 = __shfl(s_l, ie1, 64);
        float a0v = as_[sq0 * NHEAD2 + hq];
        float a1v = as_[sq1 * NHEAD2 + hq];
        float w0d = (p + ie0 < end) ? __expf(lrelu(a0v + advq)) : 0.f;
        float w1d = (p + ie1 < end) ? __expf(lrelu(a1v + advq)) : 0.f;
#pragma unroll
        for (int k = 0; k < 4; k++) {
            int i = e_lo + 4 * k;
            float wk = (k < 2) ? __shfl(w0d, i * 8 + hj, 64)
                               : __shfl(w1d, i * 8 + hj - 64, 64);
            unsigned x = g[k].x, y = g[k].y;
            acc0 += wk * __uint_as_float(x << 16);
            acc1 += wk * __uint_as_float(x & 0xffff0000u);
            acc2 += wk * __uint_as_float(y << 16);
            acc3 += wk * __uint_as_float(y & 0xffff0000u);
            accd += wk;
        }
    }
    acc0 += __shfl_xor(acc0, 16, 64); acc0 += __shfl_xor(acc0, 32, 64);
    acc1 += __shfl_xor(acc1, 16, 64); acc1 += __shfl_xor(acc1, 32, 64);
    acc2 += __shfl_xor(acc2, 16, 64); acc2 += __shfl_xor(acc2, 32, 64);
    acc3 += __shfl_xor(acc3, 16, 64); acc3 += __shfl_xor(acc3, 32, 64);
    accd += __shfl_xor(accd, 16, 64); accd += __shfl_xor(accd, 32, 64);
    if (l < 16) {
        float4 b4 = ((const float4*)bias)[cg];
        float4 outp;
        outp.x = elu(acc0 / accd + b4.x);
        outp.y = elu(acc1 / accd + b4.y);
        outp.z = elu(acc2 / accd + b4.z);
        outp.w = elu(acc3 / accd + b4.w);
        *(float4*)(xout + (long)d * F2 + 4 * cg) = outp;
    }
}

// ---------------- pair predictor ----------------

__global__ void pair_kernel(const float* __restrict__ x, const int* __restrict__ n1,
                            const int* __restrict__ n2, const float* __restrict__ linW,
                            const float* __restrict__ linb, float* __restrict__ y, int P) {
    int idx = blockIdx.x * blockDim.x + threadIdx.x;
    if (idx >= P) return;
    const float4* xa = (const float4*)(x + (long)n1[idx] * F2);
    const float4* xb = (const float4*)(x + (long)n2[idx] * F2);
    float a0 = linb[0], a1 = linb[1];
#pragma unroll
    for (int k4 = 0; k4 < F2 / 4; k4++) {
        float4 v = xa[k4];
        int k = k4 * 4;
        a0 += v.x * linW[2 * k] + v.y * linW[2 * (k + 1)] + v.z * linW[2 * (k + 2)] + v.w * linW[2 * (k + 3)];
        a1 += v.x * linW[2 * k + 1] + v.y * linW[2 * (k + 1) + 1] + v.z * linW[2 * (k + 2) + 1] + v.w * linW[2 * (k + 3) + 1];
    }
#pragma unroll
    for (int k4 = 0; k4 < F2 / 4; k4++) {
        float4 v = xb[k4];
        int k = F2 + k4 * 4;
        a0 += v.x * linW[2 * k] + v.y * linW[2 * (k + 1)] + v.z * linW[2 * (k + 2)] + v.w * linW[2 * (k + 3)];
        a1 += v.x * linW[2 * k + 1] + v.y * linW[2 * (k + 1) + 1] + v.z * linW[2 * (k + 2) + 1] + v.w * linW[2 * (k + 3) + 1];
    }
    y[2 * idx]     = 1.f / (1.f + __expf(-a0));
    y[2 * idx + 1] = 1.f / (1.f + __expf(-a1));
}

// ---------------- launch ----------------

extern "C" void kernel_launch(void* const* d_in, const int* in_sizes, int n_in,
                              void* d_out, int out_size, void* d_ws, size_t ws_size,
                              hipStream_t stream) {
    const float* features = (const float*)d_in[0];
    const int*   ei       = (const int*)d_in[1];
    const int*   n1       = (const int*)d_in[2];
    const int*   n2       = (const int*)d_in[3];
    const float* W1       = (const float*)d_in[4];
    const float* att_s1   = (const float*)d_in[5];
    const float* att_d1   = (const float*)d_in[6];
    const float* b1       = (const float*)d_in[7];
    const float* W2       = (const float*)d_in[8];
    const float* att_s2   = (const float*)d_in[9];
    const float* att_d2   = (const float*)d_in[10];
    const float* b2       = (const float*)d_in[11];
    const float* linW     = (const float*)d_in[12];
    const float* linb     = (const float*)d_in[13];

    const int N = in_sizes[0] / NUM_FEA;      // 50000
    const int E = in_sizes[1] / 2;            // 800000
    const int P = in_sizes[2];                // 16384
    const int Etot = E + N;                   // 850000

    const int nblk = (N + MROWS - 1) / MROWS;    // 391
    const int NPAD = nblk * MROWS;               // 50048
    const int nsb = (N + 255) / 256;             // 196
    const int ndeg = (Etot + 255) / 256;         // 3321

    float* ws = (float*)d_ws;
    long o = 0;
    float* h1r  = ws + o; o += (long)N * F1 / 2;             // h1b bf16
    float* xr   = ws + o; o += ((long)NPAD * KP + 1) / 2;    // Xbf then x1bf
    float* as1  = ws + o; o += (long)N * NHEAD1;
    float* ad1  = ws + o; o += (long)N * NHEAD1;
    float* h2r  = ws + o; o += (long)N * F2 / 2;             // h2b bf16
    float* as2  = ws + o; o += (long)N * NHEAD2;
    float* ad2  = ws + o; o += (long)N * NHEAD2;
    float* w1r  = ws + o; o += ((long)NC1 * KP + 1) / 2;     // Wt1 bf16 (incl att cols)
    float* w2r  = ws + o; o += ((long)NW2R * KP2 + 1) / 2;   // Wt2 bf16 (incl att cols)
    int* rowstart = (int*)(ws + o); o += N + 1;
    int* esrc = (int*)(ws + o); o += Etot;
    int* epos = (int*)(ws + o); o += Etot;
    int* cnt  = (int*)(ws + o); o += N;
    int* part = (int*)(ws + o); o += N;
    int* bsum = (int*)(ws + o); o += 256;

    ushort_t* h1b  = (ushort_t*)h1r;
    ushort_t* Xbf  = (ushort_t*)xr;
    ushort_t* x1bf = (ushort_t*)xr;    // after Xbf dead
    ushort_t* h2b  = (ushort_t*)h2r;
    ushort_t* Wt1  = (ushort_t*)w1r;
    ushort_t* Wt2  = (ushort_t*)w2r;

    float* y_out = (float*)d_out;
    float* x_out = (float*)d_out + (long)2 * P;

    hipMemsetAsync(cnt, 0, (size_t)N * sizeof(int), stream);

    long totX = (long)NPAD * KP;
    long totConv = totX + (long)NC1 * KP + (long)NW2R * KP2;

    // combo 1: conversions || degree histogram (+epos)
    conv_deg_kernel<<<NCVB + ndeg, 256, 0, stream>>>(
        features, Xbf, W1, att_s1, att_d1, Wt1, W2, att_s2, att_d2, Wt2,
        ei, cnt, epos, N, totX, totConv, E, Etot);

    // scans
    scan1_kernel<<<nsb, 256, 0, stream>>>(cnt, part, bsum, N);
    scan3_kernel<<<nsb, 256, 0, stream>>>(part, bsum, rowstart, N, Etot, nsb);

    // combo 2: GEMM1 (h1 + as1 + ad1) || CSR fill
    gemm1_fill_kernel<<<nblk + ndeg, 256, 0, stream>>>(
        Xbf, Wt1, h1b, as1, ad1, ei, rowstart, epos, esrc, N, E, Etot, nblk);

    gather1_kernel<<<(N + 3) / 4, 256, 0, stream>>>(rowstart, esrc, as1, ad1, h1b, b1, x1bf, N);

    // layer 2
    gemm2_mfma<<<nblk, 256, 0, stream>>>(x1bf, Wt2, h2b, as2, ad2, N);
    gather2_kernel<<<(N + 3) / 4, 256, 0, stream>>>(rowstart, esrc, as2, ad2, h2b, b2, x_out, N);

    // pair predictor
    pair_kernel<<<(P + 255) / 256, 256, 0, stream>>>(x_out, n1, n2, linW, linb, y_out, P);
}